// Round 8
// baseline (873.688 us; speedup 1.0000x reference)
//
#include <hip/hip_runtime.h>
#include <stdint.h>

typedef unsigned short u16;
typedef __bf16 bf16x8 __attribute__((ext_vector_type(8)));
typedef float f32x4 __attribute__((ext_vector_type(4)));

// ---------------------------------------------------------------------------
// EideticPhysicsAttention: N=65536 tokens, HID=512, H=8 heads, D=64, G=64.
//   conv  : split f32 -> (hi,lo) bf16 planes for x and W_x
//   K1    gemm_split : xp = x @ W_x.T + b_x   (split-bf16 MFMA, xp in d_out)
//   K2    k2_route   : MFMA logits+t1 (split-bf16), in-register threefry-
//                      gumbel + temperature + softmax -> wcat hi/lo planes
//                      (per-16-token m-blocks, launch_bounds(256,4))
//   K3    k3_pool    : tok_num[h,g,d] = sum_n x_mid*w ; also nrm[h,g]
//   K4a   k4_attn    : per-head 64-token attention -> o[h,g,d]
//   K4b   k4b_m2     : M2T[j][hg] hi/lo = sum_d o[hg][d]*W_out[j][h*64+d]
//   K5    gemm_split : out = wcat @ M2T.T + b_out      (overwrites d_out)
// ---------------------------------------------------------------------------

__device__ __forceinline__ u16 f2bf(float f) {   // RNE bf16
  uint32_t u = __float_as_uint(f);
  uint32_t r = u + 0x7fffu + ((u >> 16) & 1u);
  return (u16)(r >> 16);
}
__device__ __forceinline__ float bf2f(u16 h) {
  return __uint_as_float(((uint32_t)h) << 16);
}

union BF8 { bf16x8 v; u16 u[8]; uint4 q4; };

__device__ __forceinline__ float gelu_fast(float x) {
  // 0.5*x*(1+tanh(z)) == x / (1 + exp(-2z)),  z = c*(x + 0.044715 x^3)
  const float c = 0.79788456080286535588f;
  float z = c * fmaf(0.044715f, x * x * x, x);
  return x / (1.0f + __expf(-2.0f * z));
}

__device__ __forceinline__ uint32_t rotl32(uint32_t v, int s) {
  return (v << s) | (v >> (32 - s));
}

// JAX threefry2x32, key=(0,1) from jax.random.key(1), partitionable path.
__device__ __forceinline__ uint32_t threefry_bits(uint32_t idx) {
  const uint32_t k0 = 0u, k1 = 1u;
  const uint32_t k2 = 0x1BD11BDAu ^ k0 ^ k1;
  uint32_t x0 = 0u + k0;
  uint32_t x1 = idx + k1;
#define TF_R(r) { x0 += x1; x1 = rotl32(x1, r); x1 ^= x0; }
  TF_R(13) TF_R(15) TF_R(26) TF_R(6)
  x0 += k1; x1 += k2 + 1u;
  TF_R(17) TF_R(29) TF_R(16) TF_R(24)
  x0 += k2; x1 += k0 + 2u;
  TF_R(13) TF_R(15) TF_R(26) TF_R(6)
  x0 += k0; x1 += k1 + 3u;
  TF_R(17) TF_R(29) TF_R(16) TF_R(24)
  x0 += k1; x1 += k2 + 4u;
  TF_R(13) TF_R(15) TF_R(26) TF_R(6)
  x0 += k2; x1 += k0 + 5u;
#undef TF_R
  return x0 ^ x1;
}

__device__ __forceinline__ void gload_lds16(const void* g, void* l) {
  __builtin_amdgcn_global_load_lds(
      (const __attribute__((address_space(1))) void*)g,
      (__attribute__((address_space(3))) void*)l, 16, 0, 0);
}

// ---------------------------------------------------------------------------
// conv_split: f32 -> hi/lo bf16 planes (grid-stride over float4 quads)
// ---------------------------------------------------------------------------
__global__ __launch_bounds__(256) void conv_split(
    const float* __restrict__ in, u16* __restrict__ hi, u16* __restrict__ lo,
    int nq)
{
  for (int i = blockIdx.x * 256 + threadIdx.x; i < nq; i += gridDim.x * 256) {
    float4 v = ((const float4*)in)[i];
    ushort4 h, l;
    h.x = f2bf(v.x); l.x = f2bf(v.x - bf2f(h.x));
    h.y = f2bf(v.y); l.y = f2bf(v.y - bf2f(h.y));
    h.z = f2bf(v.z); l.z = f2bf(v.z - bf2f(h.z));
    h.w = f2bf(v.w); l.w = f2bf(v.w - bf2f(h.w));
    ((ushort4*)hi)[i] = h;
    ((ushort4*)lo)[i] = l;
  }
}

// ---------------------------------------------------------------------------
// gemm_split: C[m][j] = sum_k (Ah+Al)[m][k]*(Bh+Bl)[j][k] + bias[j]
// M=65536, N=512, K=512; 128x128 tile, BK=32, 4 waves, 16x16x32 MFMA.
// ---------------------------------------------------------------------------
__global__ __launch_bounds__(256) void gemm_split(
    const u16* __restrict__ Ah, const u16* __restrict__ Al,
    const u16* __restrict__ Bh, const u16* __restrict__ Bl,
    const float* __restrict__ bias, float* __restrict__ C)
{
  __shared__ u16 lds[4][4096];   // [Ah,Al,Bh,Bl][128 rows * 32 k] = 32 KB
  const int tid = threadIdx.x;
  const int lane = tid & 63;
  const int w = tid >> 6;
  const int bn = blockIdx.x & 3;
  const int bm = blockIdx.x >> 2;
  const int wr = w >> 1, wc = w & 1;

  f32x4 acc[4][4];
#pragma unroll
  for (int m = 0; m < 4; ++m)
#pragma unroll
    for (int n = 0; n < 4; ++n) acc[m][n] = (f32x4){0.f, 0.f, 0.f, 0.f};

  const int srow = lane >> 2;
  const int scol = (lane & 3) * 8;

  for (int kt = 0; kt < 16; ++kt) {
    const int k0 = kt * 32;
    __syncthreads();
#pragma unroll
    for (int i = 0; i < 8; ++i) {
      const int mat = i & 3;
      const int rb = w * 2 + (i >> 2);
      const int row = rb * 16 + srow;
      const u16* base = (mat == 0) ? Ah : (mat == 1) ? Al
                       : (mat == 2) ? Bh : Bl;
      const int tbase = (mat < 2) ? bm * 128 : bn * 128;
      const u16* src = base + (size_t)(tbase + row) * 512 + k0 + scol;
      gload_lds16(src, &lds[mat][rb * 512]);
    }
    __syncthreads();

    bf16x8 ah[4], al[4], bh_[4], bl_[4];
    const int co = (lane >> 4) * 8;
    const int rr = lane & 15;
#pragma unroll
    for (int f = 0; f < 4; ++f) {
      const int ra  = (wr * 64 + f * 16 + rr) * 32 + co;
      const int rb2 = (wc * 64 + f * 16 + rr) * 32 + co;
      ah[f]  = *(const bf16x8*)&lds[0][ra];
      al[f]  = *(const bf16x8*)&lds[1][ra];
      bh_[f] = *(const bf16x8*)&lds[2][rb2];
      bl_[f] = *(const bf16x8*)&lds[3][rb2];
    }
#pragma unroll
    for (int m = 0; m < 4; ++m)
#pragma unroll
      for (int n = 0; n < 4; ++n) {
        acc[m][n] = __builtin_amdgcn_mfma_f32_16x16x32_bf16(ah[m], bh_[n], acc[m][n], 0, 0, 0);
        acc[m][n] = __builtin_amdgcn_mfma_f32_16x16x32_bf16(ah[m], bl_[n], acc[m][n], 0, 0, 0);
        acc[m][n] = __builtin_amdgcn_mfma_f32_16x16x32_bf16(al[m], bh_[n], acc[m][n], 0, 0, 0);
      }
  }

  const int cn0 = lane & 15;
  const int rm0 = (lane >> 4) * 4;
#pragma unroll
  for (int n = 0; n < 4; ++n) {
    const int ng = bn * 128 + wc * 64 + n * 16 + cn0;
    const float bv = bias[ng];
#pragma unroll
    for (int m = 0; m < 4; ++m) {
      const int mg = bm * 128 + wr * 64 + m * 16 + rm0;
#pragma unroll
      for (int r = 0; r < 4; ++r)
        C[(size_t)(mg + r) * 512 + ng] = acc[m][n][r] + bv;
    }
  }
}

// ---------------------------------------------------------------------------
// K2: MFMA routing. Block = 4 waves; each wave processes 4 x 16-token
// m-blocks of one head (256 tokens/block). W_cat=[W_slice;W_t1] staged
// pre-fragmented (hi/lo) in LDS once. Per m-block: 48 MFMA (split-bf16,
// K=64, 128 cols), temperature, threefry-gumbel, softmax, direct
// fragment-layout stores. Per-m processing keeps only acc[8]+ah/al live ->
// VGPR <=128 (launch_bounds(256,4)) for 4 waves/SIMD.
// ---------------------------------------------------------------------------
__global__ __launch_bounds__(256, 4) void k2_route(
    const float* __restrict__ xp, const float* __restrict__ Wsl,
    const float* __restrict__ bsl, const float* __restrict__ Wt1,
    const float* __restrict__ bt1, const float* __restrict__ Wt2,
    const float* __restrict__ bt2, const float* __restrict__ tbias,
    u16* __restrict__ wh, u16* __restrict__ wl)
{
  __shared__ u16 Wf[2][8][2][64][8];      // frag-ordered W planes, 32 KB

  const int tid = threadIdx.x;
  const int l = tid & 63, wid = tid >> 6;
  const int l15 = l & 15, q = l >> 4;
  const int h = blockIdx.x >> 8;
  const int chunk = blockIdx.x & 255;

  // ---- stage W fragments (once per block) ----
#pragma unroll
  for (int it = 0; it < 8; ++it) {
    const int slot = tid + it * 256;       // 0..2047
    const int p = slot >> 10;
    const int rest = slot & 1023;
    const int nn = rest >> 7;
    const int kk = (rest >> 6) & 1;
    const int sl = rest & 63;
    const int row = nn * 16 + (sl & 15);
    const int kb = kk * 32 + (sl >> 4) * 8;
    const float* src = (row < 64) ? (Wsl + row * 64 + kb)
                                  : (Wt1 + (row - 64) * 64 + kb);
#pragma unroll
    for (int e = 0; e < 8; ++e) {
      const float v = src[e];
      const u16 hb = f2bf(v);
      Wf[p][nn][kk][sl][e] = (p == 0) ? hb : f2bf(v - bf2f(hb));
    }
  }
  __syncthreads();

  // per-lane column constants (col = j*16 + l15)
  float bslv[4], bt1v[4], wt2v[4];
#pragma unroll
  for (int j = 0; j < 4; ++j) {
    bslv[j] = bsl[j * 16 + l15];
    bt1v[j] = bt1[j * 16 + l15];
    wt2v[j] = Wt2[j * 16 + l15];
  }
  const float bt2v = bt2[0], tbv = tbias[h];

#pragma unroll 1
  for (int tm = 0; tm < 4; ++tm) {
    // token base for this 16-token m-block
    const int n0t = chunk * 256 + (tm >> 1) * 128 + wid * 32 + (tm & 1) * 16;

    // ---- A fragments: xp f32 -> split bf16 in registers ----
    bf16x8 ah[2], al[2];
#pragma unroll
    for (int kk = 0; kk < 2; ++kk) {
      const float* sp = xp + (size_t)(n0t + l15) * 512 + h * 64
                        + kk * 32 + q * 8;
      float4 v0 = *(const float4*)sp;
      float4 v1 = *(const float4*)(sp + 4);
      float vv[8] = {v0.x, v0.y, v0.z, v0.w, v1.x, v1.y, v1.z, v1.w};
      BF8 hv, lv;
#pragma unroll
      for (int e = 0; e < 8; ++e) {
        const u16 hb = f2bf(vv[e]);
        hv.u[e] = hb;
        lv.u[e] = f2bf(vv[e] - bf2f(hb));
      }
      ah[kk] = hv.v; al[kk] = lv.v;
    }

    // ---- MFMA: [16 tok] x [128 cols], K=64, 3-term ----
    f32x4 acc[8];
#pragma unroll
    for (int n = 0; n < 8; ++n) acc[n] = (f32x4){0.f, 0.f, 0.f, 0.f};
#pragma unroll
    for (int kk = 0; kk < 2; ++kk)
#pragma unroll
      for (int nn = 0; nn < 8; ++nn) {
        BF8 whf, wlf;
        whf.q4 = *(const uint4*)&Wf[0][nn][kk][l][0];
        wlf.q4 = *(const uint4*)&Wf[1][nn][kk][l][0];
        acc[nn] = __builtin_amdgcn_mfma_f32_16x16x32_bf16(ah[kk], whf.v, acc[nn], 0, 0, 0);
        acc[nn] = __builtin_amdgcn_mfma_f32_16x16x32_bf16(ah[kk], wlf.v, acc[nn], 0, 0, 0);
        acc[nn] = __builtin_amdgcn_mfma_f32_16x16x32_bf16(al[kk], whf.v, acc[nn], 0, 0, 0);
      }

    // C layout: token lt = q*4 + r ; col = n*16 + l15

    // ---- temperature per r: reduce t1 half across 16-lane group ----
    float itv[4];
#pragma unroll
    for (int r = 0; r < 4; ++r) {
      float part = 0.f;
#pragma unroll
      for (int j = 0; j < 4; ++j)
        part += gelu_fast(acc[4 + j][r] + bt1v[j]) * wt2v[j];
      part += __shfl_xor(part, 1);
      part += __shfl_xor(part, 2);
      part += __shfl_xor(part, 4);
      part += __shfl_xor(part, 8);
      const float tval = gelu_fast(part + bt2v) + tbv;
      itv[r] = 1.0f / fmaxf(tval, 0.01f);
    }

    // ---- logits: bias + threefry-gumbel + /t ----
    const uint32_t pbase = ((uint32_t)((h << 16) | (n0t + q * 4))) << 6;
#pragma unroll
    for (int j = 0; j < 4; ++j) {
      const uint32_t cc = j * 16 + l15;
#pragma unroll
      for (int r = 0; r < 4; ++r) {
        const uint32_t bits = threefry_bits(pbase + ((uint32_t)r << 6) + cc);
        const float u = __uint_as_float((bits >> 9) | 0x3f800000u) - 1.0f;
        const float gin = -__logf(u + 1e-8f);
        const float gn = -__logf(gin + 1e-8f);
        acc[j][r] = (acc[j][r] + bslv[j] + gn) * itv[r];
      }
    }

    // ---- softmax over cols (16-lane group x 4 frags) ----
#pragma unroll
    for (int r = 0; r < 4; ++r) {
      float mx = fmaxf(fmaxf(acc[0][r], acc[1][r]),
                       fmaxf(acc[2][r], acc[3][r]));
      mx = fmaxf(mx, __shfl_xor(mx, 1));
      mx = fmaxf(mx, __shfl_xor(mx, 2));
      mx = fmaxf(mx, __shfl_xor(mx, 4));
      mx = fmaxf(mx, __shfl_xor(mx, 8));
      float se = 0.f;
#pragma unroll
      for (int j = 0; j < 4; ++j) {
        const float e = __expf(acc[j][r] - mx);
        acc[j][r] = e;
        se += e;
      }
      se += __shfl_xor(se, 1);
      se += __shfl_xor(se, 2);
      se += __shfl_xor(se, 4);
      se += __shfl_xor(se, 8);
      const float inv = 1.0f / se;
#pragma unroll
      for (int j = 0; j < 4; ++j) acc[j][r] *= inv;
    }

    // ---- direct fragment-layout stores (16 consecutive u16 per group) ----
#pragma unroll
    for (int j = 0; j < 4; ++j)
#pragma unroll
      for (int r = 0; r < 4; ++r) {
        const float wv = acc[j][r];
        const u16 hb = f2bf(wv);
        const u16 lb = f2bf(wv - bf2f(hb));
        const size_t idx =
            (size_t)(n0t + q * 4 + r) * 512 + h * 64 + j * 16 + l15;
        wh[idx] = hb;
        wl[idx] = lb;
      }
  }
}

// ---------------------------------------------------------------------------
// K3: tok_num[h,g,d] = sum_n w[n,g]*x[n,d] ; nrm[h,g] = sum_n w[n,g].
// No-LDS streaming outer product. Grid = 8 heads x 256 chunks (256 tokens);
// 4 waves x 64 tokens each, lane owns an 8x8 (g,d) patch in registers.
// ---------------------------------------------------------------------------
__global__ __launch_bounds__(256) void k3_pool(
    const float* __restrict__ xp, const u16* __restrict__ wh,
    const u16* __restrict__ wl, float* __restrict__ tok_num,
    float* __restrict__ nrm)
{
  __shared__ float red[64][65];
  __shared__ float redn[64];
  const int h = blockIdx.x >> 8;
  const int chunk = blockIdx.x & 255;
  const int lane = threadIdx.x & 63;
  const int wid = threadIdx.x >> 6;
  const int i0 = (lane & 7) * 8;   // d block
  const int j0 = (lane >> 3) * 8;  // g block
  const int jq = lane >> 3;

  float acc[8][8];
#pragma unroll
  for (int j = 0; j < 8; ++j)
#pragma unroll
    for (int i = 0; i < 8; ++i) acc[j][i] = 0.f;
  float csum[8];
#pragma unroll
  for (int j = 0; j < 8; ++j) csum[j] = 0.f;

  const int n0 = chunk * 256 + wid * 64;
#pragma unroll 2
  for (int t = 0; t < 64; ++t) {
    const size_t base = (size_t)(n0 + t) * 512 + h * 64;
    const float4 x0 = *(const float4*)(xp + base + i0);
    const float4 x1 = *(const float4*)(xp + base + i0 + 4);
    const ushort4 h0 = *(const ushort4*)(wh + base + j0);
    const ushort4 h1 = *(const ushort4*)(wh + base + j0 + 4);
    const ushort4 l0 = *(const ushort4*)(wl + base + j0);
    const ushort4 l1 = *(const ushort4*)(wl + base + j0 + 4);
    const float x8[8] = {x0.x, x0.y, x0.z, x0.w, x1.x, x1.y, x1.z, x1.w};
    const float w8[8] = {
        bf2f(h0.x) + bf2f(l0.x), bf2f(h0.y) + bf2f(l0.y),
        bf2f(h0.z) + bf2f(l0.z), bf2f(h0.w) + bf2f(l0.w),
        bf2f(h1.x) + bf2f(l1.x), bf2f(h1.y) + bf2f(l1.y),
        bf2f(h1.z) + bf2f(l1.z), bf2f(h1.w) + bf2f(l1.w)};
#pragma unroll
    for (int j = 0; j < 8; ++j) csum[j] += w8[j];
#pragma unroll
    for (int j = 0; j < 8; ++j)
#pragma unroll
      for (int i = 0; i < 8; ++i)
        acc[j][i] = fmaf(w8[j], x8[i], acc[j][i]);
  }

  // sequential cross-wave reduce (swizzled: bank = full-rank in lane)
  for (int w = 0; w < 4; ++w) {
    if (wid == w) {
      if (w == 0) {
#pragma unroll
        for (int j = 0; j < 8; ++j)
#pragma unroll
          for (int i = 0; i < 8; ++i)
            red[j0 + j][i0 | (i ^ jq)] = acc[j][i];
        if ((lane & 7) == 0) {
#pragma unroll
          for (int j = 0; j < 8; ++j) redn[j0 + j] = csum[j];
        }
      } else {
#pragma unroll
        for (int j = 0; j < 8; ++j)
#pragma unroll
          for (int i = 0; i < 8; ++i)
            red[j0 + j][i0 | (i ^ jq)] += acc[j][i];
        if ((lane & 7) == 0) {
#pragma unroll
          for (int j = 0; j < 8; ++j) redn[j0 + j] += csum[j];
        }
      }
    }
    __syncthreads();
  }

  for (int e = threadIdx.x; e < 4096; e += 256) {
    const int g = e >> 6, d = e & 63;
    const int col = (d & 56) | ((d & 7) ^ (g >> 3));
    atomicAdd(&tok_num[h * 4096 + e], red[g][col]);
  }
  if (threadIdx.x < 64)
    atomicAdd(&nrm[h * 64 + threadIdx.x], redn[threadIdx.x]);
}

// ---------------------------------------------------------------------------
// K4a: per-head attention over G=64 slice tokens. One block per head.
// ---------------------------------------------------------------------------
__global__ __launch_bounds__(256) void k4_attn(
    const float* __restrict__ tok_num, const float* __restrict__ nrm,
    const float* __restrict__ Wq, const float* __restrict__ Wk,
    const float* __restrict__ Wv, const float* __restrict__ Wo,
    float* __restrict__ o_out)
{
  __shared__ float T[64][65], Abuf[64][65], Bbuf[64][65], Wbuf[64][65], S2[64][65];
  const int h = blockIdx.x;
  const int tid = threadIdx.x;

  for (int e = tid; e < 4096; e += 256) {
    const int g = e >> 6, d = e & 63;
    T[g][d] = tok_num[h * 4096 + e] / (nrm[h * 64 + g] + 1e-5f);
  }
  for (int e = tid; e < 4096; e += 256) Wbuf[e >> 6][e & 63] = Wq[e];
  __syncthreads();

  const int g = tid >> 2, d0 = (tid & 3) * 16;
  float r[16];

#pragma unroll
  for (int j = 0; j < 16; ++j) r[j] = 0.f;
  for (int e = 0; e < 64; ++e) {
    const float tv = T[g][e];
#pragma unroll
    for (int j = 0; j < 16; ++j) r[j] = fmaf(tv, Wbuf[d0 + j][e], r[j]);
  }
#pragma unroll
  for (int j = 0; j < 16; ++j) Abuf[g][d0 + j] = r[j];
  __syncthreads();

  for (int e = tid; e < 4096; e += 256) Wbuf[e >> 6][e & 63] = Wk[e];
  __syncthreads();

#pragma unroll
  for (int j = 0; j < 16; ++j) r[j] = 0.f;
  for (int e = 0; e < 64; ++e) {
    const float tv = T[g][e];
#pragma unroll
    for (int j = 0; j < 16; ++j) r[j] = fmaf(tv, Wbuf[d0 + j][e], r[j]);
  }
#pragma unroll
  for (int j = 0; j < 16; ++j) Bbuf[g][d0 + j] = r[j];
  __syncthreads();

#pragma unroll
  for (int j = 0; j < 16; ++j) r[j] = 0.f;
  for (int e = 0; e < 64; ++e) {
    const float qv = Abuf[g][e] * 0.125f;
#pragma unroll
    for (int j = 0; j < 16; ++j) r[j] = fmaf(qv, Bbuf[d0 + j][e], r[j]);
  }
#pragma unroll
  for (int j = 0; j < 16; ++j) S2[g][d0 + j] = r[j];
  __syncthreads();

  if (tid < 64) {
    float mx = -1e30f;
    for (int j = 0; j < 64; ++j) mx = fmaxf(mx, S2[tid][j]);
    float sum = 0.f;
    for (int j = 0; j < 64; ++j) {
      const float e2 = expf(S2[tid][j] - mx);
      S2[tid][j] = e2;
      sum += e2;
    }
    const float inv = 1.0f / sum;
    for (int j = 0; j < 64; ++j) S2[tid][j] *= inv;
  }
  __syncthreads();

  for (int e = tid; e < 4096; e += 256) Wbuf[e >> 6][e & 63] = Wv[e];
  __syncthreads();

#pragma unroll
  for (int j = 0; j < 16; ++j) r[j] = 0.f;
  for (int e = 0; e < 64; ++e) {
    const float tv = T[g][e];
#pragma unroll
    for (int j = 0; j < 16; ++j) r[j] = fmaf(tv, Wbuf[d0 + j][e], r[j]);
  }
  __syncthreads();
#pragma unroll
  for (int j = 0; j < 16; ++j) Bbuf[g][d0 + j] = r[j];
  __syncthreads();

#pragma unroll
  for (int j = 0; j < 16; ++j) r[j] = 0.f;
  for (int e = 0; e < 64; ++e) {
    const float sv = S2[g][e];
#pragma unroll
    for (int j = 0; j < 16; ++j) r[j] = fmaf(sv, Bbuf[e][d0 + j], r[j]);
  }
  __syncthreads();
#pragma unroll
  for (int j = 0; j < 16; ++j) Abuf[g][d0 + j] = r[j];
  for (int e = tid; e < 4096; e += 256) Wbuf[e >> 6][e & 63] = Wo[e];
  __syncthreads();

#pragma unroll
  for (int j = 0; j < 16; ++j) r[j] = 0.f;
  for (int e = 0; e < 64; ++e) {
    const float ov = Abuf[g][e];
#pragma unroll
    for (int j = 0; j < 16; ++j) r[j] = fmaf(ov, Wbuf[d0 + j][e], r[j]);
  }
#pragma unroll
  for (int j = 0; j < 16; ++j) o_out[h * 4096 + g * 64 + d0 + j] = r[j];
}

// ---------------------------------------------------------------------------
// K4b: M2T[j][hg] = sum_d o[hg][d] * W_out[j][h*64+d]  -> hi/lo bf16 planes
// ---------------------------------------------------------------------------
__global__ __launch_bounds__(256) void k4b_m2(
    const float* __restrict__ o, const float* __restrict__ Wout,
    u16* __restrict__ M2h, u16* __restrict__ M2l)
{
  const int j = blockIdx.x >> 1;
  const int hg = ((blockIdx.x & 1) << 8) + threadIdx.x;
  const int h = hg >> 6;
  const float* orow = &o[hg * 64];
  const float* wrow = &Wout[j * 512 + h * 64];
  float s = 0.f;
#pragma unroll
  for (int d = 0; d < 64; ++d) s = fmaf(orow[d], wrow[d], s);
  const u16 hb = f2bf(s);
  M2h[j * 512 + hg] = hb;
  M2l[j * 512 + hg] = f2bf(s - bf2f(hb));
}

// ---------------------------------------------------------------------------
extern "C" void kernel_launch(void* const* d_in, const int* in_sizes, int n_in,
                              void* d_out, int out_size, void* d_ws, size_t ws_size,
                              hipStream_t stream)
{
  const float* x      = (const float*)d_in[0];
  const float* W_x    = (const float*)d_in[1];
  const float* b_x    = (const float*)d_in[2];
  const float* W_sl   = (const float*)d_in[3];
  const float* b_sl   = (const float*)d_in[4];
  const float* W_t1   = (const float*)d_in[5];
  const float* b_t1   = (const float*)d_in[6];
  const float* W_t2   = (const float*)d_in[7];
  const float* b_t2   = (const float*)d_in[8];
  const float* t_bias = (const float*)d_in[9];
  const float* Wq     = (const float*)d_in[10];
  const float* Wk     = (const float*)d_in[11];
  const float* Wv     = (const float*)d_in[12];
  const float* Wo     = (const float*)d_in[13];
  const float* W_out  = (const float*)d_in[14];
  const float* b_out  = (const float*)d_in[15];

  float* out = (float*)d_out;
  float* xp = out;   // xp lives in d_out; overwritten by final GEMM

  char* ws = (char*)d_ws;
  u16*   Ahi     = (u16*)(ws);                   // x hi, then wcat hi
  u16*   Alo     = (u16*)(ws + 67108864);        // x lo, then wcat lo
  u16*   Bhi     = (u16*)(ws + 134217728);       // Wx hi, then M2T hi
  u16*   Blo     = (u16*)(ws + 134742016);       // Wx lo, then M2T lo
  float* tok_num = (float*)(ws + 135266304);     // 131072 B
  float* nrm     = (float*)(ws + 135397376);     // 2048 B
  float* o_buf   = (float*)(ws + 135399424);     // 131072 B

  conv_split<<<2048, 256, 0, stream>>>(x, Ahi, Alo, 8388608);
  conv_split<<<256, 256, 0, stream>>>(W_x, Bhi, Blo, 65536);
  gemm_split<<<2048, 256, 0, stream>>>(Ahi, Alo, Bhi, Blo, b_x, xp);

  hipMemsetAsync(tok_num, 0, 133120, stream);  // tok_num + nrm (contiguous)

  k2_route<<<2048, 256, 0, stream>>>(xp, W_sl, b_sl, W_t1, b_t1, W_t2, b_t2,
                                     t_bias, Ahi, Alo);        // overwrites x-split
  k3_pool<<<2048, 256, 0, stream>>>(xp, Ahi, Alo, tok_num, nrm);
  k4_attn<<<8, 256, 0, stream>>>(tok_num, nrm, Wq, Wk, Wv, Wo, o_buf);
  k4b_m2<<<1024, 256, 0, stream>>>(o_buf, W_out, Bhi, Blo);    // overwrites Wx-split
  gemm_split<<<2048, 256, 0, stream>>>(Ahi, Alo, Bhi, Blo, b_out, out);
}

// Round 9
// 630.928 us; speedup vs baseline: 1.3848x; 1.3848x over previous
//
#include <hip/hip_runtime.h>
#include <stdint.h>

typedef unsigned short u16;
typedef __bf16 bf16x8 __attribute__((ext_vector_type(8)));
typedef float f32x4 __attribute__((ext_vector_type(4)));

// ---------------------------------------------------------------------------
// EideticPhysicsAttention: N=65536 tokens, HID=512, H=8 heads, D=64, G=64.
//   conv  : split f32 -> (hi,lo) bf16 planes for x and W_x
//   K1    gemm_split : xp = x @ W_x.T + b_x   (split-bf16 MFMA, xp in d_out)
//   K2    k2_route   : MFMA logits+t1 (split-bf16), threefry-gumbel,
//                      softmax; per-m-block; per-wave LDS transpose ->
//                      coalesced plane stores.  launch_bounds(256,4).
//   K3    k3_pool    : tok_num[h,g,d] = sum_n x_mid*w ; nrm[h,g]
//                      (streaming outer product, 1024 blocks, 1-tok prefetch)
//   K4a   k4_attn    : per-head 64-token attention -> o[h,g,d]
//   K4b   k4b_m2     : M2T[j][hg] hi/lo = sum_d o[hg][d]*W_out[j][h*64+d]
//   K5    gemm_split : out = wcat @ M2T.T + b_out      (overwrites d_out)
// ---------------------------------------------------------------------------

__device__ __forceinline__ u16 f2bf(float f) {   // RNE bf16
  uint32_t u = __float_as_uint(f);
  uint32_t r = u + 0x7fffu + ((u >> 16) & 1u);
  return (u16)(r >> 16);
}
__device__ __forceinline__ float bf2f(u16 h) {
  return __uint_as_float(((uint32_t)h) << 16);
}

union BF8 { bf16x8 v; u16 u[8]; uint4 q4; };

__device__ __forceinline__ float gelu_fast(float x) {
  // 0.5*x*(1+tanh(z)) == x / (1 + exp(-2z)),  z = c*(x + 0.044715 x^3)
  const float c = 0.79788456080286535588f;
  float z = c * fmaf(0.044715f, x * x * x, x);
  return x / (1.0f + __expf(-2.0f * z));
}

__device__ __forceinline__ uint32_t rotl32(uint32_t v, int s) {
  return (v << s) | (v >> (32 - s));
}

// JAX threefry2x32, key=(0,1) from jax.random.key(1), partitionable path.
__device__ __forceinline__ uint32_t threefry_bits(uint32_t idx) {
  const uint32_t k0 = 0u, k1 = 1u;
  const uint32_t k2 = 0x1BD11BDAu ^ k0 ^ k1;
  uint32_t x0 = 0u + k0;
  uint32_t x1 = idx + k1;
#define TF_R(r) { x0 += x1; x1 = rotl32(x1, r); x1 ^= x0; }
  TF_R(13) TF_R(15) TF_R(26) TF_R(6)
  x0 += k1; x1 += k2 + 1u;
  TF_R(17) TF_R(29) TF_R(16) TF_R(24)
  x0 += k2; x1 += k0 + 2u;
  TF_R(13) TF_R(15) TF_R(26) TF_R(6)
  x0 += k0; x1 += k1 + 3u;
  TF_R(17) TF_R(29) TF_R(16) TF_R(24)
  x0 += k1; x1 += k2 + 4u;
  TF_R(13) TF_R(15) TF_R(26) TF_R(6)
  x0 += k2; x1 += k0 + 5u;
#undef TF_R
  return x0 ^ x1;
}

__device__ __forceinline__ void gload_lds16(const void* g, void* l) {
  __builtin_amdgcn_global_load_lds(
      (const __attribute__((address_space(1))) void*)g,
      (__attribute__((address_space(3))) void*)l, 16, 0, 0);
}

// ---------------------------------------------------------------------------
// conv_split: f32 -> hi/lo bf16 planes (grid-stride over float4 quads)
// ---------------------------------------------------------------------------
__global__ __launch_bounds__(256) void conv_split(
    const float* __restrict__ in, u16* __restrict__ hi, u16* __restrict__ lo,
    int nq)
{
  for (int i = blockIdx.x * 256 + threadIdx.x; i < nq; i += gridDim.x * 256) {
    float4 v = ((const float4*)in)[i];
    ushort4 h, l;
    h.x = f2bf(v.x); l.x = f2bf(v.x - bf2f(h.x));
    h.y = f2bf(v.y); l.y = f2bf(v.y - bf2f(h.y));
    h.z = f2bf(v.z); l.z = f2bf(v.z - bf2f(h.z));
    h.w = f2bf(v.w); l.w = f2bf(v.w - bf2f(h.w));
    ((ushort4*)hi)[i] = h;
    ((ushort4*)lo)[i] = l;
  }
}

// ---------------------------------------------------------------------------
// gemm_split: C[m][j] = sum_k (Ah+Al)[m][k]*(Bh+Bl)[j][k] + bias[j]
// M=65536, N=512, K=512; 128x128 tile, BK=32, 4 waves, 16x16x32 MFMA.
// ---------------------------------------------------------------------------
__global__ __launch_bounds__(256) void gemm_split(
    const u16* __restrict__ Ah, const u16* __restrict__ Al,
    const u16* __restrict__ Bh, const u16* __restrict__ Bl,
    const float* __restrict__ bias, float* __restrict__ C)
{
  __shared__ u16 lds[4][4096];   // [Ah,Al,Bh,Bl][128 rows * 32 k] = 32 KB
  const int tid = threadIdx.x;
  const int lane = tid & 63;
  const int w = tid >> 6;
  const int bn = blockIdx.x & 3;
  const int bm = blockIdx.x >> 2;
  const int wr = w >> 1, wc = w & 1;

  f32x4 acc[4][4];
#pragma unroll
  for (int m = 0; m < 4; ++m)
#pragma unroll
    for (int n = 0; n < 4; ++n) acc[m][n] = (f32x4){0.f, 0.f, 0.f, 0.f};

  const int srow = lane >> 2;
  const int scol = (lane & 3) * 8;

  for (int kt = 0; kt < 16; ++kt) {
    const int k0 = kt * 32;
    __syncthreads();
#pragma unroll
    for (int i = 0; i < 8; ++i) {
      const int mat = i & 3;
      const int rb = w * 2 + (i >> 2);
      const int row = rb * 16 + srow;
      const u16* base = (mat == 0) ? Ah : (mat == 1) ? Al
                       : (mat == 2) ? Bh : Bl;
      const int tbase = (mat < 2) ? bm * 128 : bn * 128;
      const u16* src = base + (size_t)(tbase + row) * 512 + k0 + scol;
      gload_lds16(src, &lds[mat][rb * 512]);
    }
    __syncthreads();

    bf16x8 ah[4], al[4], bh_[4], bl_[4];
    const int co = (lane >> 4) * 8;
    const int rr = lane & 15;
#pragma unroll
    for (int f = 0; f < 4; ++f) {
      const int ra  = (wr * 64 + f * 16 + rr) * 32 + co;
      const int rb2 = (wc * 64 + f * 16 + rr) * 32 + co;
      ah[f]  = *(const bf16x8*)&lds[0][ra];
      al[f]  = *(const bf16x8*)&lds[1][ra];
      bh_[f] = *(const bf16x8*)&lds[2][rb2];
      bl_[f] = *(const bf16x8*)&lds[3][rb2];
    }
#pragma unroll
    for (int m = 0; m < 4; ++m)
#pragma unroll
      for (int n = 0; n < 4; ++n) {
        acc[m][n] = __builtin_amdgcn_mfma_f32_16x16x32_bf16(ah[m], bh_[n], acc[m][n], 0, 0, 0);
        acc[m][n] = __builtin_amdgcn_mfma_f32_16x16x32_bf16(ah[m], bl_[n], acc[m][n], 0, 0, 0);
        acc[m][n] = __builtin_amdgcn_mfma_f32_16x16x32_bf16(al[m], bh_[n], acc[m][n], 0, 0, 0);
      }
  }

  const int cn0 = lane & 15;
  const int rm0 = (lane >> 4) * 4;
#pragma unroll
  for (int n = 0; n < 4; ++n) {
    const int ng = bn * 128 + wc * 64 + n * 16 + cn0;
    const float bv = bias[ng];
#pragma unroll
    for (int m = 0; m < 4; ++m) {
      const int mg = bm * 128 + wr * 64 + m * 16 + rm0;
#pragma unroll
      for (int r = 0; r < 4; ++r)
        C[(size_t)(mg + r) * 512 + ng] = acc[m][n][r] + bv;
    }
  }
}

// ---------------------------------------------------------------------------
// K2: MFMA routing. Block = 4 waves; each wave: 4 x 16-token m-blocks of one
// head (256 tokens/block). Per m-block: 48 MFMA (split-bf16, K=64, 128 cols),
// temperature, threefry-gumbel, softmax, then per-wave LDS transpose
// (wbuf[4][16][68], hi|lo packed u32) -> coalesced uint2 plane stores.
// LDS = 32K (Wf) + 17.4K (wbuf) -> 3 blocks/CU; VGPR<=128 via (256,4).
// ---------------------------------------------------------------------------
__global__ __launch_bounds__(256, 4) void k2_route(
    const float* __restrict__ xp, const float* __restrict__ Wsl,
    const float* __restrict__ bsl, const float* __restrict__ Wt1,
    const float* __restrict__ bt1, const float* __restrict__ Wt2,
    const float* __restrict__ bt2, const float* __restrict__ tbias,
    u16* __restrict__ wh, u16* __restrict__ wl)
{
  __shared__ u16 Wf[2][8][2][64][8];      // frag-ordered W planes, 32 KB
  __shared__ uint32_t wbuf[4][16][68];    // per-wave transpose, hi|lo<<16

  const int tid = threadIdx.x;
  const int l = tid & 63, wid = tid >> 6;
  const int l15 = l & 15, q = l >> 4;
  const int h = blockIdx.x >> 8;
  const int chunk = blockIdx.x & 255;

  // ---- stage W fragments (once per block) ----
#pragma unroll
  for (int it = 0; it < 8; ++it) {
    const int slot = tid + it * 256;       // 0..2047
    const int p = slot >> 10;
    const int rest = slot & 1023;
    const int nn = rest >> 7;
    const int kk = (rest >> 6) & 1;
    const int sl = rest & 63;
    const int row = nn * 16 + (sl & 15);
    const int kb = kk * 32 + (sl >> 4) * 8;
    const float* src = (row < 64) ? (Wsl + row * 64 + kb)
                                  : (Wt1 + (row - 64) * 64 + kb);
#pragma unroll
    for (int e = 0; e < 8; ++e) {
      const float v = src[e];
      const u16 hb = f2bf(v);
      Wf[p][nn][kk][sl][e] = (p == 0) ? hb : f2bf(v - bf2f(hb));
    }
  }
  __syncthreads();

  // per-lane column constants (col = j*16 + l15)
  float bslv[4], bt1v[4], wt2v[4];
#pragma unroll
  for (int j = 0; j < 4; ++j) {
    bslv[j] = bsl[j * 16 + l15];
    bt1v[j] = bt1[j * 16 + l15];
    wt2v[j] = Wt2[j * 16 + l15];
  }
  const float bt2v = bt2[0], tbv = tbias[h];

#pragma unroll 1
  for (int tm = 0; tm < 4; ++tm) {
    // token base for this 16-token m-block
    const int n0t = chunk * 256 + (tm >> 1) * 128 + wid * 32 + (tm & 1) * 16;

    // ---- A fragments: xp f32 -> split bf16 in registers ----
    bf16x8 ah[2], al[2];
#pragma unroll
    for (int kk = 0; kk < 2; ++kk) {
      const float* sp = xp + (size_t)(n0t + l15) * 512 + h * 64
                        + kk * 32 + q * 8;
      float4 v0 = *(const float4*)sp;
      float4 v1 = *(const float4*)(sp + 4);
      float vv[8] = {v0.x, v0.y, v0.z, v0.w, v1.x, v1.y, v1.z, v1.w};
      BF8 hv, lv;
#pragma unroll
      for (int e = 0; e < 8; ++e) {
        const u16 hb = f2bf(vv[e]);
        hv.u[e] = hb;
        lv.u[e] = f2bf(vv[e] - bf2f(hb));
      }
      ah[kk] = hv.v; al[kk] = lv.v;
    }

    // ---- MFMA: [16 tok] x [128 cols], K=64, 3-term ----
    f32x4 acc[8];
#pragma unroll
    for (int n = 0; n < 8; ++n) acc[n] = (f32x4){0.f, 0.f, 0.f, 0.f};
#pragma unroll
    for (int kk = 0; kk < 2; ++kk)
#pragma unroll
      for (int nn = 0; nn < 8; ++nn) {
        BF8 whf, wlf;
        whf.q4 = *(const uint4*)&Wf[0][nn][kk][l][0];
        wlf.q4 = *(const uint4*)&Wf[1][nn][kk][l][0];
        acc[nn] = __builtin_amdgcn_mfma_f32_16x16x32_bf16(ah[kk], whf.v, acc[nn], 0, 0, 0);
        acc[nn] = __builtin_amdgcn_mfma_f32_16x16x32_bf16(ah[kk], wlf.v, acc[nn], 0, 0, 0);
        acc[nn] = __builtin_amdgcn_mfma_f32_16x16x32_bf16(al[kk], whf.v, acc[nn], 0, 0, 0);
      }

    // C layout: token lt = q*4 + r ; col = n*16 + l15

    // ---- temperature per r: reduce t1 half across 16-lane group ----
    float itv[4];
#pragma unroll
    for (int r = 0; r < 4; ++r) {
      float part = 0.f;
#pragma unroll
      for (int j = 0; j < 4; ++j)
        part += gelu_fast(acc[4 + j][r] + bt1v[j]) * wt2v[j];
      part += __shfl_xor(part, 1);
      part += __shfl_xor(part, 2);
      part += __shfl_xor(part, 4);
      part += __shfl_xor(part, 8);
      const float tval = gelu_fast(part + bt2v) + tbv;
      itv[r] = 1.0f / fmaxf(tval, 0.01f);
    }

    // ---- logits: bias + threefry-gumbel + /t ----
    const uint32_t pbase = ((uint32_t)((h << 16) | (n0t + q * 4))) << 6;
#pragma unroll
    for (int j = 0; j < 4; ++j) {
      const uint32_t cc = j * 16 + l15;
#pragma unroll
      for (int r = 0; r < 4; ++r) {
        const uint32_t bits = threefry_bits(pbase + ((uint32_t)r << 6) + cc);
        const float u = __uint_as_float((bits >> 9) | 0x3f800000u) - 1.0f;
        const float gin = -__logf(u + 1e-8f);
        const float gn = -__logf(gin + 1e-8f);
        acc[j][r] = (acc[j][r] + bslv[j] + gn) * itv[r];
      }
    }

    // ---- softmax over cols (16-lane group x 4 frags) ----
#pragma unroll
    for (int r = 0; r < 4; ++r) {
      float mx = fmaxf(fmaxf(acc[0][r], acc[1][r]),
                       fmaxf(acc[2][r], acc[3][r]));
      mx = fmaxf(mx, __shfl_xor(mx, 1));
      mx = fmaxf(mx, __shfl_xor(mx, 2));
      mx = fmaxf(mx, __shfl_xor(mx, 4));
      mx = fmaxf(mx, __shfl_xor(mx, 8));
      float se = 0.f;
#pragma unroll
      for (int j = 0; j < 4; ++j) {
        const float e = __expf(acc[j][r] - mx);
        acc[j][r] = e;
        se += e;
      }
      se += __shfl_xor(se, 1);
      se += __shfl_xor(se, 2);
      se += __shfl_xor(se, 4);
      se += __shfl_xor(se, 8);
      const float inv = 1.0f / se;
#pragma unroll
      for (int j = 0; j < 4; ++j) acc[j][r] *= inv;
    }

    // ---- pack hi|lo into per-wave LDS transpose ----
#pragma unroll
    for (int j = 0; j < 4; ++j)
#pragma unroll
      for (int r = 0; r < 4; ++r) {
        const float wv = acc[j][r];
        const u16 hb = f2bf(wv);
        const u16 lb = f2bf(wv - bf2f(hb));
        wbuf[wid][q * 4 + r][j * 16 + l15] = (uint32_t)hb | ((uint32_t)lb << 16);
      }
    __syncthreads();

    // ---- coalesced plane stores: 16 tok x 16 uint4 = 256 -> 64 lanes x 4 ----
#pragma unroll
    for (int it = 0; it < 4; ++it) {
      const int t = l >> 2;
      const int qq = (l & 3) + it * 4;    // 0..15
      const uint4 v = *(const uint4*)&wbuf[wid][t][qq * 4];
      const uint32_t hp0 = (v.x & 0xffffu) | (v.y << 16);
      const uint32_t hp1 = (v.z & 0xffffu) | (v.w << 16);
      const uint32_t lp0 = (v.x >> 16) | (v.y & 0xffff0000u);
      const uint32_t lp1 = (v.z >> 16) | (v.w & 0xffff0000u);
      const size_t b32 = (size_t)(n0t + t) * 256 + h * 32 + qq * 2;
      *(uint2*)((uint32_t*)wh + b32) = make_uint2(hp0, hp1);
      *(uint2*)((uint32_t*)wl + b32) = make_uint2(lp0, lp1);
    }
    __syncthreads();
  }
}

// ---------------------------------------------------------------------------
// K3: tok_num[h,g,d] = sum_n w[n,g]*x[n,d] ; nrm[h,g] = sum_n w[n,g].
// No-LDS streaming outer product. Grid = 8 heads x 128 chunks (512 tokens);
// 4 waves x 128 tokens each; 1-token register prefetch pipeline so each
// wave's loads for token t+1 are in flight under token t's 64 FMAs.
// Cross-wave reduce: sequential LDS accumulate with XOR-swizzled columns.
// ---------------------------------------------------------------------------
__global__ __launch_bounds__(256) void k3_pool(
    const float* __restrict__ xp, const u16* __restrict__ wh,
    const u16* __restrict__ wl, float* __restrict__ tok_num,
    float* __restrict__ nrm)
{
  __shared__ float red[64][65];
  __shared__ float redn[64];
  const int h = blockIdx.x >> 7;
  const int chunk = blockIdx.x & 127;
  const int lane = threadIdx.x & 63;
  const int wid = threadIdx.x >> 6;
  const int i0 = (lane & 7) * 8;   // d block
  const int j0 = (lane >> 3) * 8;  // g block
  const int jq = lane >> 3;

  float acc[8][8];
#pragma unroll
  for (int j = 0; j < 8; ++j)
#pragma unroll
    for (int i = 0; i < 8; ++i) acc[j][i] = 0.f;
  float csum[8];
#pragma unroll
  for (int j = 0; j < 8; ++j) csum[j] = 0.f;

  const int n0 = chunk * 512 + wid * 128;
  const size_t base0 = (size_t)n0 * 512 + h * 64;

  // prefetch token 0
  float4 nx0 = *(const float4*)(xp + base0 + i0);
  float4 nx1 = *(const float4*)(xp + base0 + i0 + 4);
  ushort4 nh0 = *(const ushort4*)(wh + base0 + j0);
  ushort4 nh1 = *(const ushort4*)(wh + base0 + j0 + 4);
  ushort4 nl0 = *(const ushort4*)(wl + base0 + j0);
  ushort4 nl1 = *(const ushort4*)(wl + base0 + j0 + 4);

#pragma unroll 2
  for (int t = 0; t < 128; ++t) {
    const float4 x0 = nx0, x1 = nx1;
    const ushort4 h0 = nh0, h1 = nh1, l0 = nl0, l1 = nl1;
    if (t < 127) {
      const size_t nb = base0 + (size_t)(t + 1) * 512;
      nx0 = *(const float4*)(xp + nb + i0);
      nx1 = *(const float4*)(xp + nb + i0 + 4);
      nh0 = *(const ushort4*)(wh + nb + j0);
      nh1 = *(const ushort4*)(wh + nb + j0 + 4);
      nl0 = *(const ushort4*)(wl + nb + j0);
      nl1 = *(const ushort4*)(wl + nb + j0 + 4);
    }
    const float x8[8] = {x0.x, x0.y, x0.z, x0.w, x1.x, x1.y, x1.z, x1.w};
    const float w8[8] = {
        bf2f(h0.x) + bf2f(l0.x), bf2f(h0.y) + bf2f(l0.y),
        bf2f(h0.z) + bf2f(l0.z), bf2f(h0.w) + bf2f(l0.w),
        bf2f(h1.x) + bf2f(l1.x), bf2f(h1.y) + bf2f(l1.y),
        bf2f(h1.z) + bf2f(l1.z), bf2f(h1.w) + bf2f(l1.w)};
#pragma unroll
    for (int j = 0; j < 8; ++j) csum[j] += w8[j];
#pragma unroll
    for (int j = 0; j < 8; ++j)
#pragma unroll
      for (int i = 0; i < 8; ++i)
        acc[j][i] = fmaf(w8[j], x8[i], acc[j][i]);
  }

  // sequential cross-wave reduce (swizzled: bank = full-rank in lane)
  for (int w = 0; w < 4; ++w) {
    if (wid == w) {
      if (w == 0) {
#pragma unroll
        for (int j = 0; j < 8; ++j)
#pragma unroll
          for (int i = 0; i < 8; ++i)
            red[j0 + j][i0 | (i ^ jq)] = acc[j][i];
        if ((lane & 7) == 0) {
#pragma unroll
          for (int j = 0; j < 8; ++j) redn[j0 + j] = csum[j];
        }
      } else {
#pragma unroll
        for (int j = 0; j < 8; ++j)
#pragma unroll
          for (int i = 0; i < 8; ++i)
            red[j0 + j][i0 | (i ^ jq)] += acc[j][i];
        if ((lane & 7) == 0) {
#pragma unroll
          for (int j = 0; j < 8; ++j) redn[j0 + j] += csum[j];
        }
      }
    }
    __syncthreads();
  }

  for (int e = threadIdx.x; e < 4096; e += 256) {
    const int g = e >> 6, d = e & 63;
    const int col = (d & 56) | ((d & 7) ^ (g >> 3));
    atomicAdd(&tok_num[h * 4096 + e], red[g][col]);
  }
  if (threadIdx.x < 64)
    atomicAdd(&nrm[h * 64 + threadIdx.x], redn[threadIdx.x]);
}

// ---------------------------------------------------------------------------
// K4a: per-head attention over G=64 slice tokens. One block per head.
// ---------------------------------------------------------------------------
__global__ __launch_bounds__(256) void k4_attn(
    const float* __restrict__ tok_num, const float* __restrict__ nrm,
    const float* __restrict__ Wq, const float* __restrict__ Wk,
    const float* __restrict__ Wv, const float* __restrict__ Wo,
    float* __restrict__ o_out)
{
  __shared__ float T[64][65], Abuf[64][65], Bbuf[64][65], Wbuf[64][65], S2[64][65];
  const int h = blockIdx.x;
  const int tid = threadIdx.x;

  for (int e = tid; e < 4096; e += 256) {
    const int g = e >> 6, d = e & 63;
    T[g][d] = tok_num[h * 4096 + e] / (nrm[h * 64 + g] + 1e-5f);
  }
  for (int e = tid; e < 4096; e += 256) Wbuf[e >> 6][e & 63] = Wq[e];
  __syncthreads();

  const int g = tid >> 2, d0 = (tid & 3) * 16;
  float r[16];

#pragma unroll
  for (int j = 0; j < 16; ++j) r[j] = 0.f;
  for (int e = 0; e < 64; ++e) {
    const float tv = T[g][e];
#pragma unroll
    for (int j = 0; j < 16; ++j) r[j] = fmaf(tv, Wbuf[d0 + j][e], r[j]);
  }
#pragma unroll
  for (int j = 0; j < 16; ++j) Abuf[g][d0 + j] = r[j];
  __syncthreads();

  for (int e = tid; e < 4096; e += 256) Wbuf[e >> 6][e & 63] = Wk[e];
  __syncthreads();

#pragma unroll
  for (int j = 0; j < 16; ++j) r[j] = 0.f;
  for (int e = 0; e < 64; ++e) {
    const float tv = T[g][e];
#pragma unroll
    for (int j = 0; j < 16; ++j) r[j] = fmaf(tv, Wbuf[d0 + j][e], r[j]);
  }
#pragma unroll
  for (int j = 0; j < 16; ++j) Bbuf[g][d0 + j] = r[j];
  __syncthreads();

#pragma unroll
  for (int j = 0; j < 16; ++j) r[j] = 0.f;
  for (int e = 0; e < 64; ++e) {
    const float qv = Abuf[g][e] * 0.125f;
#pragma unroll
    for (int j = 0; j < 16; ++j) r[j] = fmaf(qv, Bbuf[d0 + j][e], r[j]);
  }
#pragma unroll
  for (int j = 0; j < 16; ++j) S2[g][d0 + j] = r[j];
  __syncthreads();

  if (tid < 64) {
    float mx = -1e30f;
    for (int j = 0; j < 64; ++j) mx = fmaxf(mx, S2[tid][j]);
    float sum = 0.f;
    for (int j = 0; j < 64; ++j) {
      const float e2 = expf(S2[tid][j] - mx);
      S2[tid][j] = e2;
      sum += e2;
    }
    const float inv = 1.0f / sum;
    for (int j = 0; j < 64; ++j) S2[tid][j] *= inv;
  }
  __syncthreads();

  for (int e = tid; e < 4096; e += 256) Wbuf[e >> 6][e & 63] = Wv[e];
  __syncthreads();

#pragma unroll
  for (int j = 0; j < 16; ++j) r[j] = 0.f;
  for (int e = 0; e < 64; ++e) {
    const float tv = T[g][e];
#pragma unroll
    for (int j = 0; j < 16; ++j) r[j] = fmaf(tv, Wbuf[d0 + j][e], r[j]);
  }
  __syncthreads();
#pragma unroll
  for (int j = 0; j < 16; ++j) Bbuf[g][d0 + j] = r[j];
  __syncthreads();

#pragma unroll
  for (int j = 0; j < 16; ++j) r[j] = 0.f;
  for (int e = 0; e < 64; ++e) {
    const float sv = S2[g][e];
#pragma unroll
    for (int j = 0; j < 16; ++j) r[j] = fmaf(sv, Bbuf[e][d0 + j], r[j]);
  }
  __syncthreads();
#pragma unroll
  for (int j = 0; j < 16; ++j) Abuf[g][d0 + j] = r[j];
  for (int e = tid; e < 4096; e += 256) Wbuf[e >> 6][e & 63] = Wo[e];
  __syncthreads();

#pragma unroll
  for (int j = 0; j < 16; ++j) r[j] = 0.f;
  for (int e = 0; e < 64; ++e) {
    const float ov = Abuf[g][e];
#pragma unroll
    for (int j = 0; j < 16; ++j) r[j] = fmaf(ov, Wbuf[d0 + j][e], r[j]);
  }
#pragma unroll
  for (int j = 0; j < 16; ++j) o_out[h * 4096 + g * 64 + d0 + j] = r[j];
}

// ---------------------------------------------------------------------------
// K4b: M2T[j][hg] = sum_d o[hg][d] * W_out[j][h*64+d]  -> hi/lo bf16 planes
// ---------------------------------------------------------------------------
__global__ __launch_bounds__(256) void k4b_m2(
    const float* __restrict__ o, const float* __restrict__ Wout,
    u16* __restrict__ M2h, u16* __restrict__ M2l)
{
  const int j = blockIdx.x >> 1;
  const int hg = ((blockIdx.x & 1) << 8) + threadIdx.x;
  const int h = hg >> 6;
  const float* orow = &o[hg * 64];
  const float* wrow = &Wout[j * 512 + h * 64];
  float s = 0.f;
#pragma unroll
  for (int d = 0; d < 64; ++d) s = fmaf(orow[d], wrow[d], s);
  const u16 hb = f2bf(s);
  M2h[j * 512 + hg] = hb;
  M2l[j * 512 + hg] = f2bf(s - bf2f(hb));
}

// ---------------------------------------------------------------------------
extern "C" void kernel_launch(void* const* d_in, const int* in_sizes, int n_in,
                              void* d_out, int out_size, void* d_ws, size_t ws_size,
                              hipStream_t stream)
{
  const float* x      = (const float*)d_in[0];
  const float* W_x    = (const float*)d_in[1];
  const float* b_x    = (const float*)d_in[2];
  const float* W_sl   = (const float*)d_in[3];
  const float* b_sl   = (const float*)d_in[4];
  const float* W_t1   = (const float*)d_in[5];
  const float* b_t1   = (const float*)d_in[6];
  const float* W_t2   = (const float*)d_in[7];
  const float* b_t2   = (const float*)d_in[8];
  const float* t_bias = (const float*)d_in[9];
  const float* Wq     = (const float*)d_in[10];
  const float* Wk     = (const float*)d_in[11];
  const float* Wv     = (const float*)d_in[12];
  const float* Wo     = (const float*)d_in[13];
  const float* W_out  = (const float*)d_in[14];
  const float* b_out  = (const float*)d_in[15];

  float* out = (float*)d_out;
  float* xp = out;   // xp lives in d_out; overwritten by final GEMM

  char* ws = (char*)d_ws;
  u16*   Ahi     = (u16*)(ws);                   // x hi, then wcat hi
  u16*   Alo     = (u16*)(ws + 67108864);        // x lo, then wcat lo
  u16*   Bhi     = (u16*)(ws + 134217728);       // Wx hi, then M2T hi
  u16*   Blo     = (u16*)(ws + 134742016);       // Wx lo, then M2T lo
  float* tok_num = (float*)(ws + 135266304);     // 131072 B
  float* nrm     = (float*)(ws + 135397376);     // 2048 B
  float* o_buf   = (float*)(ws + 135399424);     // 131072 B

  conv_split<<<2048, 256, 0, stream>>>(x, Ahi, Alo, 8388608);
  conv_split<<<256, 256, 0, stream>>>(W_x, Bhi, Blo, 65536);
  gemm_split<<<2048, 256, 0, stream>>>(Ahi, Alo, Bhi, Blo, b_x, xp);

  hipMemsetAsync(tok_num, 0, 133120, stream);  // tok_num + nrm (contiguous)

  k2_route<<<2048, 256, 0, stream>>>(xp, W_sl, b_sl, W_t1, b_t1, W_t2, b_t2,
                                     t_bias, Ahi, Alo);        // overwrites x-split
  k3_pool<<<1024, 256, 0, stream>>>(xp, Ahi, Alo, tok_num, nrm);
  k4_attn<<<8, 256, 0, stream>>>(tok_num, nrm, Wq, Wk, Wv, Wo, o_buf);
  k4b_m2<<<1024, 256, 0, stream>>>(o_buf, W_out, Bhi, Blo);    // overwrites Wx-split
  gemm_split<<<2048, 256, 0, stream>>>(Ahi, Alo, Bhi, Blo, b_out, out);
}

// Round 10
// 602.046 us; speedup vs baseline: 1.4512x; 1.0480x over previous
//
#include <hip/hip_runtime.h>
#include <stdint.h>

typedef unsigned short u16;
typedef __bf16 bf16x8 __attribute__((ext_vector_type(8)));
typedef float f32x4 __attribute__((ext_vector_type(4)));

// ---------------------------------------------------------------------------
// EideticPhysicsAttention: N=65536 tokens, HID=512, H=8 heads, D=64, G=64.
//   conv  : split f32 -> (hi,lo) bf16 planes for x and W_x
//   K1    gemm_split : xp = x @ W_x.T + b_x   (split-bf16 MFMA, xp in d_out)
//   K2    k2_route   : MFMA logits+t1, threefry-gumbel, softmax ->
//                      wcat PACKED u32 plane (hi|lo<<16)
//   K3    k3_pool    : tok_num[h,g,d] = sum_n x_mid*w ; nrm[h,g]
//                      (streaming outer product, packed w, 4 loads/token)
//   K4a   k4_attn    : per-head 64-token attention -> o[h,g,d]
//   K4b   k4b_m2     : M2T[j][hg] hi/lo = sum_d o[hg][d]*W_out[j][h*64+d]
//   K5    gemm_packA : out = wcat @ M2T.T + b_out      (packed-A GEMM)
// ---------------------------------------------------------------------------

__device__ __forceinline__ u16 f2bf(float f) {   // RNE bf16
  uint32_t u = __float_as_uint(f);
  uint32_t r = u + 0x7fffu + ((u >> 16) & 1u);
  return (u16)(r >> 16);
}
__device__ __forceinline__ float bf2f(u16 h) {
  return __uint_as_float(((uint32_t)h) << 16);
}

union BF8 { bf16x8 v; u16 u[8]; uint4 q4; };

__device__ __forceinline__ float gelu_fast(float x) {
  const float c = 0.79788456080286535588f;
  float z = c * fmaf(0.044715f, x * x * x, x);
  return x / (1.0f + __expf(-2.0f * z));
}

__device__ __forceinline__ uint32_t rotl32(uint32_t v, int s) {
  return (v << s) | (v >> (32 - s));
}

// JAX threefry2x32, key=(0,1) from jax.random.key(1), partitionable path.
__device__ __forceinline__ uint32_t threefry_bits(uint32_t idx) {
  const uint32_t k0 = 0u, k1 = 1u;
  const uint32_t k2 = 0x1BD11BDAu ^ k0 ^ k1;
  uint32_t x0 = 0u + k0;
  uint32_t x1 = idx + k1;
#define TF_R(r) { x0 += x1; x1 = rotl32(x1, r); x1 ^= x0; }
  TF_R(13) TF_R(15) TF_R(26) TF_R(6)
  x0 += k1; x1 += k2 + 1u;
  TF_R(17) TF_R(29) TF_R(16) TF_R(24)
  x0 += k2; x1 += k0 + 2u;
  TF_R(13) TF_R(15) TF_R(26) TF_R(6)
  x0 += k0; x1 += k1 + 3u;
  TF_R(17) TF_R(29) TF_R(16) TF_R(24)
  x0 += k1; x1 += k2 + 4u;
  TF_R(13) TF_R(15) TF_R(26) TF_R(6)
  x0 += k2; x1 += k0 + 5u;
#undef TF_R
  return x0 ^ x1;
}

__device__ __forceinline__ void gload_lds16(const void* g, void* l) {
  __builtin_amdgcn_global_load_lds(
      (const __attribute__((address_space(1))) void*)g,
      (__attribute__((address_space(3))) void*)l, 16, 0, 0);
}

// ---------------------------------------------------------------------------
// conv_split: f32 -> hi/lo bf16 planes (grid-stride over float4 quads)
// ---------------------------------------------------------------------------
__global__ __launch_bounds__(256) void conv_split(
    const float* __restrict__ in, u16* __restrict__ hi, u16* __restrict__ lo,
    int nq)
{
  for (int i = blockIdx.x * 256 + threadIdx.x; i < nq; i += gridDim.x * 256) {
    float4 v = ((const float4*)in)[i];
    ushort4 h, l;
    h.x = f2bf(v.x); l.x = f2bf(v.x - bf2f(h.x));
    h.y = f2bf(v.y); l.y = f2bf(v.y - bf2f(h.y));
    h.z = f2bf(v.z); l.z = f2bf(v.z - bf2f(h.z));
    h.w = f2bf(v.w); l.w = f2bf(v.w - bf2f(h.w));
    ((ushort4*)hi)[i] = h;
    ((ushort4*)lo)[i] = l;
  }
}

// ---------------------------------------------------------------------------
// gemm_split: C[m][j] = sum_k (Ah+Al)[m][k]*(Bh+Bl)[j][k] + bias[j]
// M=65536, N=512, K=512; 128x128 tile, BK=32, 4 waves, 16x16x32 MFMA.
// XCD-swizzled block ids: all 4 bn of a bm-panel on the same XCD.
// ---------------------------------------------------------------------------
__global__ __launch_bounds__(256) void gemm_split(
    const u16* __restrict__ Ah, const u16* __restrict__ Al,
    const u16* __restrict__ Bh, const u16* __restrict__ Bl,
    const float* __restrict__ bias, float* __restrict__ C)
{
  __shared__ u16 lds[4][4096];   // [Ah,Al,Bh,Bl][128 rows * 32 k] = 32 KB
  const int tid = threadIdx.x;
  const int lane = tid & 63;
  const int w = tid >> 6;
  const int vid = (blockIdx.x & 7) * 256 + (blockIdx.x >> 3);  // XCD swizzle
  const int bn = vid & 3;
  const int bm = vid >> 2;
  const int wr = w >> 1, wc = w & 1;

  f32x4 acc[4][4];
#pragma unroll
  for (int m = 0; m < 4; ++m)
#pragma unroll
    for (int n = 0; n < 4; ++n) acc[m][n] = (f32x4){0.f, 0.f, 0.f, 0.f};

  const int srow = lane >> 2;
  const int scol = (lane & 3) * 8;

  for (int kt = 0; kt < 16; ++kt) {
    const int k0 = kt * 32;
    __syncthreads();
#pragma unroll
    for (int i = 0; i < 8; ++i) {
      const int mat = i & 3;
      const int rb = w * 2 + (i >> 2);
      const int row = rb * 16 + srow;
      const u16* base = (mat == 0) ? Ah : (mat == 1) ? Al
                       : (mat == 2) ? Bh : Bl;
      const int tbase = (mat < 2) ? bm * 128 : bn * 128;
      const u16* src = base + (size_t)(tbase + row) * 512 + k0 + scol;
      gload_lds16(src, &lds[mat][rb * 512]);
    }
    __syncthreads();

    bf16x8 ah[4], al[4], bh_[4], bl_[4];
    const int co = (lane >> 4) * 8;
    const int rr = lane & 15;
#pragma unroll
    for (int f = 0; f < 4; ++f) {
      const int ra  = (wr * 64 + f * 16 + rr) * 32 + co;
      const int rb2 = (wc * 64 + f * 16 + rr) * 32 + co;
      ah[f]  = *(const bf16x8*)&lds[0][ra];
      al[f]  = *(const bf16x8*)&lds[1][ra];
      bh_[f] = *(const bf16x8*)&lds[2][rb2];
      bl_[f] = *(const bf16x8*)&lds[3][rb2];
    }
#pragma unroll
    for (int m = 0; m < 4; ++m)
#pragma unroll
      for (int n = 0; n < 4; ++n) {
        acc[m][n] = __builtin_amdgcn_mfma_f32_16x16x32_bf16(ah[m], bh_[n], acc[m][n], 0, 0, 0);
        acc[m][n] = __builtin_amdgcn_mfma_f32_16x16x32_bf16(ah[m], bl_[n], acc[m][n], 0, 0, 0);
        acc[m][n] = __builtin_amdgcn_mfma_f32_16x16x32_bf16(al[m], bh_[n], acc[m][n], 0, 0, 0);
      }
  }

  const int cn0 = lane & 15;
  const int rm0 = (lane >> 4) * 4;
#pragma unroll
  for (int n = 0; n < 4; ++n) {
    const int ng = bn * 128 + wc * 64 + n * 16 + cn0;
    const float bv = bias[ng];
#pragma unroll
    for (int m = 0; m < 4; ++m) {
      const int mg = bm * 128 + wr * 64 + m * 16 + rm0;
#pragma unroll
      for (int r = 0; r < 4; ++r)
        C[(size_t)(mg + r) * 512 + ng] = acc[m][n][r] + bv;
    }
  }
}

// ---------------------------------------------------------------------------
// gemm_packA: A is PACKED u32 (hi|lo<<16); B as hi/lo u16 planes.
// C[m][j] = sum_k (Ah+Al)[m][k]*(Bh+Bl)[j][k] + bias[j]; same tiling.
// ---------------------------------------------------------------------------
__global__ __launch_bounds__(256) void gemm_packA(
    const uint32_t* __restrict__ A, const u16* __restrict__ Bh,
    const u16* __restrict__ Bl, const float* __restrict__ bias,
    float* __restrict__ C)
{
  __shared__ uint32_t ldsA[128 * 32];            // 16 KB
  __shared__ u16 ldsBh[128 * 32], ldsBl[128 * 32]; // 8 + 8 KB
  const int tid = threadIdx.x;
  const int lane = tid & 63;
  const int w = tid >> 6;
  const int vid = (blockIdx.x & 7) * 256 + (blockIdx.x >> 3);  // XCD swizzle
  const int bn = vid & 3;
  const int bm = vid >> 2;
  const int wr = w >> 1, wcq = w & 1;

  f32x4 acc[4][4];
#pragma unroll
  for (int m = 0; m < 4; ++m)
#pragma unroll
    for (int n = 0; n < 4; ++n) acc[m][n] = (f32x4){0.f, 0.f, 0.f, 0.f};

  for (int kt = 0; kt < 16; ++kt) {
    const int k0 = kt * 32;
    __syncthreads();
    // A: 16 groups of 8 rows (8 rows * 32 u32 = 1 KB per wave-issue)
#pragma unroll
    for (int i = 0; i < 4; ++i) {
      const int rb8 = i * 4 + w;
      const int row = rb8 * 8 + (lane >> 3);
      const uint32_t* src =
          A + (size_t)(bm * 128 + row) * 512 + k0 + (lane & 7) * 4;
      gload_lds16(src, &ldsA[rb8 * 8 * 32]);
    }
    // B: 8 groups of 16 rows per plane (16 rows * 32 u16 = 1 KB)
#pragma unroll
    for (int i = 0; i < 2; ++i) {
      const int rb16 = i * 4 + w;
      const int row = rb16 * 16 + (lane >> 2);
      const int sc = (lane & 3) * 8;
      gload_lds16(Bh + (size_t)(bn * 128 + row) * 512 + k0 + sc,
                  &ldsBh[rb16 * 16 * 32]);
      gload_lds16(Bl + (size_t)(bn * 128 + row) * 512 + k0 + sc,
                  &ldsBl[rb16 * 16 * 32]);
    }
    __syncthreads();

    bf16x8 ah[4], al[4], bh_[4], bl_[4];
    const int co = (lane >> 4) * 8;
    const int rr = lane & 15;
#pragma unroll
    for (int f = 0; f < 4; ++f) {
      const int ra = (wr * 64 + f * 16 + rr) * 32 + co;
      const uint4 p0 = *(const uint4*)&ldsA[ra];
      const uint4 p1 = *(const uint4*)&ldsA[ra + 4];
      BF8 hv, lv;
      uint32_t* hd = (uint32_t*)&hv.q4;
      uint32_t* ld = (uint32_t*)&lv.q4;
      hd[0] = __builtin_amdgcn_perm(p0.y, p0.x, 0x05040100u);
      hd[1] = __builtin_amdgcn_perm(p0.w, p0.z, 0x05040100u);
      hd[2] = __builtin_amdgcn_perm(p1.y, p1.x, 0x05040100u);
      hd[3] = __builtin_amdgcn_perm(p1.w, p1.z, 0x05040100u);
      ld[0] = __builtin_amdgcn_perm(p0.y, p0.x, 0x07060302u);
      ld[1] = __builtin_amdgcn_perm(p0.w, p0.z, 0x07060302u);
      ld[2] = __builtin_amdgcn_perm(p1.y, p1.x, 0x07060302u);
      ld[3] = __builtin_amdgcn_perm(p1.w, p1.z, 0x07060302u);
      ah[f] = hv.v; al[f] = lv.v;
      const int rb2 = (wcq * 64 + f * 16 + rr) * 32 + co;
      bh_[f] = *(const bf16x8*)&ldsBh[rb2];
      bl_[f] = *(const bf16x8*)&ldsBl[rb2];
    }
#pragma unroll
    for (int m = 0; m < 4; ++m)
#pragma unroll
      for (int n = 0; n < 4; ++n) {
        acc[m][n] = __builtin_amdgcn_mfma_f32_16x16x32_bf16(ah[m], bh_[n], acc[m][n], 0, 0, 0);
        acc[m][n] = __builtin_amdgcn_mfma_f32_16x16x32_bf16(ah[m], bl_[n], acc[m][n], 0, 0, 0);
        acc[m][n] = __builtin_amdgcn_mfma_f32_16x16x32_bf16(al[m], bh_[n], acc[m][n], 0, 0, 0);
      }
  }

  const int cn0 = lane & 15;
  const int rm0 = (lane >> 4) * 4;
#pragma unroll
  for (int n = 0; n < 4; ++n) {
    const int ng = bn * 128 + wcq * 64 + n * 16 + cn0;
    const float bv = bias[ng];
#pragma unroll
    for (int m = 0; m < 4; ++m) {
      const int mg = bm * 128 + wr * 64 + m * 16 + rm0;
#pragma unroll
      for (int r = 0; r < 4; ++r)
        C[(size_t)(mg + r) * 512 + ng] = acc[m][n][r] + bv;
    }
  }
}

// ---------------------------------------------------------------------------
// K2: MFMA routing. Block = 4 waves; each wave: 4 x 16-token m-blocks of one
// head. Per m-block: 48 MFMA, temperature, threefry-gumbel, softmax, then
// per-wave LDS transpose -> coalesced PACKED u32 stores (hi|lo<<16).
// ---------------------------------------------------------------------------
__global__ __launch_bounds__(256, 4) void k2_route(
    const float* __restrict__ xp, const float* __restrict__ Wsl,
    const float* __restrict__ bsl, const float* __restrict__ Wt1,
    const float* __restrict__ bt1, const float* __restrict__ Wt2,
    const float* __restrict__ bt2, const float* __restrict__ tbias,
    uint32_t* __restrict__ wcp)
{
  __shared__ u16 Wf[2][8][2][64][8];      // frag-ordered W planes, 32 KB
  __shared__ uint32_t wbuf[4][16][68];    // per-wave transpose, hi|lo<<16

  const int tid = threadIdx.x;
  const int l = tid & 63, wid = tid >> 6;
  const int l15 = l & 15, q = l >> 4;
  const int h = blockIdx.x >> 8;
  const int chunk = blockIdx.x & 255;

  // ---- stage W fragments (once per block) ----
#pragma unroll
  for (int it = 0; it < 8; ++it) {
    const int slot = tid + it * 256;
    const int p = slot >> 10;
    const int rest = slot & 1023;
    const int nn = rest >> 7;
    const int kk = (rest >> 6) & 1;
    const int sl = rest & 63;
    const int row = nn * 16 + (sl & 15);
    const int kb = kk * 32 + (sl >> 4) * 8;
    const float* src = (row < 64) ? (Wsl + row * 64 + kb)
                                  : (Wt1 + (row - 64) * 64 + kb);
#pragma unroll
    for (int e = 0; e < 8; ++e) {
      const float v = src[e];
      const u16 hb = f2bf(v);
      Wf[p][nn][kk][sl][e] = (p == 0) ? hb : f2bf(v - bf2f(hb));
    }
  }
  __syncthreads();

  float bslv[4], bt1v[4], wt2v[4];
#pragma unroll
  for (int j = 0; j < 4; ++j) {
    bslv[j] = bsl[j * 16 + l15];
    bt1v[j] = bt1[j * 16 + l15];
    wt2v[j] = Wt2[j * 16 + l15];
  }
  const float bt2v = bt2[0], tbv = tbias[h];

#pragma unroll 1
  for (int tm = 0; tm < 4; ++tm) {
    const int n0t = chunk * 256 + (tm >> 1) * 128 + wid * 32 + (tm & 1) * 16;

    // ---- A fragments: xp f32 -> split bf16 in registers ----
    bf16x8 ah[2], al[2];
#pragma unroll
    for (int kk = 0; kk < 2; ++kk) {
      const float* sp = xp + (size_t)(n0t + l15) * 512 + h * 64
                        + kk * 32 + q * 8;
      float4 v0 = *(const float4*)sp;
      float4 v1 = *(const float4*)(sp + 4);
      float vv[8] = {v0.x, v0.y, v0.z, v0.w, v1.x, v1.y, v1.z, v1.w};
      BF8 hv, lv;
#pragma unroll
      for (int e = 0; e < 8; ++e) {
        const u16 hb = f2bf(vv[e]);
        hv.u[e] = hb;
        lv.u[e] = f2bf(vv[e] - bf2f(hb));
      }
      ah[kk] = hv.v; al[kk] = lv.v;
    }

    // ---- MFMA: [16 tok] x [128 cols], K=64, 3-term ----
    f32x4 acc[8];
#pragma unroll
    for (int n = 0; n < 8; ++n) acc[n] = (f32x4){0.f, 0.f, 0.f, 0.f};
#pragma unroll
    for (int kk = 0; kk < 2; ++kk)
#pragma unroll
      for (int nn = 0; nn < 8; ++nn) {
        BF8 whf, wlf;
        whf.q4 = *(const uint4*)&Wf[0][nn][kk][l][0];
        wlf.q4 = *(const uint4*)&Wf[1][nn][kk][l][0];
        acc[nn] = __builtin_amdgcn_mfma_f32_16x16x32_bf16(ah[kk], whf.v, acc[nn], 0, 0, 0);
        acc[nn] = __builtin_amdgcn_mfma_f32_16x16x32_bf16(ah[kk], wlf.v, acc[nn], 0, 0, 0);
        acc[nn] = __builtin_amdgcn_mfma_f32_16x16x32_bf16(al[kk], whf.v, acc[nn], 0, 0, 0);
      }

    // ---- temperature per r ----
    float itv[4];
#pragma unroll
    for (int r = 0; r < 4; ++r) {
      float part = 0.f;
#pragma unroll
      for (int j = 0; j < 4; ++j)
        part += gelu_fast(acc[4 + j][r] + bt1v[j]) * wt2v[j];
      part += __shfl_xor(part, 1);
      part += __shfl_xor(part, 2);
      part += __shfl_xor(part, 4);
      part += __shfl_xor(part, 8);
      const float tval = gelu_fast(part + bt2v) + tbv;
      itv[r] = 1.0f / fmaxf(tval, 0.01f);
    }

    // ---- logits: bias + threefry-gumbel + /t ----
    const uint32_t pbase = ((uint32_t)((h << 16) | (n0t + q * 4))) << 6;
#pragma unroll
    for (int j = 0; j < 4; ++j) {
      const uint32_t cc = j * 16 + l15;
#pragma unroll
      for (int r = 0; r < 4; ++r) {
        const uint32_t bits = threefry_bits(pbase + ((uint32_t)r << 6) + cc);
        const float u = __uint_as_float((bits >> 9) | 0x3f800000u) - 1.0f;
        const float gin = -__logf(u + 1e-8f);
        const float gn = -__logf(gin + 1e-8f);
        acc[j][r] = (acc[j][r] + bslv[j] + gn) * itv[r];
      }
    }

    // ---- softmax over cols ----
#pragma unroll
    for (int r = 0; r < 4; ++r) {
      float mx = fmaxf(fmaxf(acc[0][r], acc[1][r]),
                       fmaxf(acc[2][r], acc[3][r]));
      mx = fmaxf(mx, __shfl_xor(mx, 1));
      mx = fmaxf(mx, __shfl_xor(mx, 2));
      mx = fmaxf(mx, __shfl_xor(mx, 4));
      mx = fmaxf(mx, __shfl_xor(mx, 8));
      float se = 0.f;
#pragma unroll
      for (int j = 0; j < 4; ++j) {
        const float e = __expf(acc[j][r] - mx);
        acc[j][r] = e;
        se += e;
      }
      se += __shfl_xor(se, 1);
      se += __shfl_xor(se, 2);
      se += __shfl_xor(se, 4);
      se += __shfl_xor(se, 8);
      const float inv = 1.0f / se;
#pragma unroll
      for (int j = 0; j < 4; ++j) acc[j][r] *= inv;
    }

    // ---- pack hi|lo into per-wave LDS transpose ----
#pragma unroll
    for (int j = 0; j < 4; ++j)
#pragma unroll
      for (int r = 0; r < 4; ++r) {
        const float wv = acc[j][r];
        const u16 hb = f2bf(wv);
        const u16 lb = f2bf(wv - bf2f(hb));
        wbuf[wid][q * 4 + r][j * 16 + l15] = (uint32_t)hb | ((uint32_t)lb << 16);
      }
    __syncthreads();

    // ---- coalesced packed stores: 16 tok x 16 uint4 -> 64 lanes x 4 ----
#pragma unroll
    for (int it = 0; it < 4; ++it) {
      const int t = l >> 2;
      const int qq = (l & 3) + it * 4;    // 0..15
      const uint4 v = *(const uint4*)&wbuf[wid][t][qq * 4];
      *(uint4*)(wcp + (size_t)(n0t + t) * 512 + h * 64 + qq * 4) = v;
    }
    __syncthreads();
  }
}

// ---------------------------------------------------------------------------
// K3: tok_num[h,g,d] = sum_n w[n,g]*x[n,d] ; nrm[h,g] = sum_n w[n,g].
// Streaming outer product; w read PACKED (2 uint4/token) + x (2 float4).
// Grid = 8 heads x 128 chunks; 4 waves x 128 tokens; 1-token prefetch.
// ---------------------------------------------------------------------------
__global__ __launch_bounds__(256) void k3_pool(
    const float* __restrict__ xp, const uint32_t* __restrict__ wcp,
    float* __restrict__ tok_num, float* __restrict__ nrm)
{
  __shared__ float red[64][65];
  __shared__ float redn[64];
  const int h = blockIdx.x >> 7;
  const int chunk = blockIdx.x & 127;
  const int lane = threadIdx.x & 63;
  const int wid = threadIdx.x >> 6;
  const int i0 = (lane & 7) * 8;   // d block
  const int j0 = (lane >> 3) * 8;  // g block
  const int jq = lane >> 3;

  float acc[8][8];
#pragma unroll
  for (int j = 0; j < 8; ++j)
#pragma unroll
    for (int i = 0; i < 8; ++i) acc[j][i] = 0.f;
  float csum[8];
#pragma unroll
  for (int j = 0; j < 8; ++j) csum[j] = 0.f;

  const int n0 = chunk * 512 + wid * 128;
  const size_t base0 = (size_t)n0 * 512 + h * 64;

  float4 nx0 = *(const float4*)(xp + base0 + i0);
  float4 nx1 = *(const float4*)(xp + base0 + i0 + 4);
  uint4 nq0 = *(const uint4*)(wcp + base0 + j0);
  uint4 nq1 = *(const uint4*)(wcp + base0 + j0 + 4);

#pragma unroll 2
  for (int t = 0; t < 128; ++t) {
    const float4 x0 = nx0, x1 = nx1;
    const uint4 q0 = nq0, q1 = nq1;
    if (t < 127) {
      const size_t nb = base0 + (size_t)(t + 1) * 512;
      nx0 = *(const float4*)(xp + nb + i0);
      nx1 = *(const float4*)(xp + nb + i0 + 4);
      nq0 = *(const uint4*)(wcp + nb + j0);
      nq1 = *(const uint4*)(wcp + nb + j0 + 4);
    }
    const float x8[8] = {x0.x, x0.y, x0.z, x0.w, x1.x, x1.y, x1.z, x1.w};
    const float w8[8] = {
        __uint_as_float(q0.x << 16) + __uint_as_float(q0.x & 0xffff0000u),
        __uint_as_float(q0.y << 16) + __uint_as_float(q0.y & 0xffff0000u),
        __uint_as_float(q0.z << 16) + __uint_as_float(q0.z & 0xffff0000u),
        __uint_as_float(q0.w << 16) + __uint_as_float(q0.w & 0xffff0000u),
        __uint_as_float(q1.x << 16) + __uint_as_float(q1.x & 0xffff0000u),
        __uint_as_float(q1.y << 16) + __uint_as_float(q1.y & 0xffff0000u),
        __uint_as_float(q1.z << 16) + __uint_as_float(q1.z & 0xffff0000u),
        __uint_as_float(q1.w << 16) + __uint_as_float(q1.w & 0xffff0000u)};
#pragma unroll
    for (int j = 0; j < 8; ++j) csum[j] += w8[j];
#pragma unroll
    for (int j = 0; j < 8; ++j)
#pragma unroll
      for (int i = 0; i < 8; ++i)
        acc[j][i] = fmaf(w8[j], x8[i], acc[j][i]);
  }

  // sequential cross-wave reduce (swizzled columns)
  for (int w = 0; w < 4; ++w) {
    if (wid == w) {
      if (w == 0) {
#pragma unroll
        for (int j = 0; j < 8; ++j)
#pragma unroll
          for (int i = 0; i < 8; ++i)
            red[j0 + j][i0 | (i ^ jq)] = acc[j][i];
        if ((lane & 7) == 0) {
#pragma unroll
          for (int j = 0; j < 8; ++j) redn[j0 + j] = csum[j];
        }
      } else {
#pragma unroll
        for (int j = 0; j < 8; ++j)
#pragma unroll
          for (int i = 0; i < 8; ++i)
            red[j0 + j][i0 | (i ^ jq)] += acc[j][i];
        if ((lane & 7) == 0) {
#pragma unroll
          for (int j = 0; j < 8; ++j) redn[j0 + j] += csum[j];
        }
      }
    }
    __syncthreads();
  }

  for (int e = threadIdx.x; e < 4096; e += 256) {
    const int g = e >> 6, d = e & 63;
    const int col = (d & 56) | ((d & 7) ^ (g >> 3));
    atomicAdd(&tok_num[h * 4096 + e], red[g][col]);
  }
  if (threadIdx.x < 64)
    atomicAdd(&nrm[h * 64 + threadIdx.x], redn[threadIdx.x]);
}

// ---------------------------------------------------------------------------
// K4a: per-head attention over G=64 slice tokens. One block per head.
// ---------------------------------------------------------------------------
__global__ __launch_bounds__(256) void k4_attn(
    const float* __restrict__ tok_num, const float* __restrict__ nrm,
    const float* __restrict__ Wq, const float* __restrict__ Wk,
    const float* __restrict__ Wv, const float* __restrict__ Wo,
    float* __restrict__ o_out)
{
  __shared__ float T[64][65], Abuf[64][65], Bbuf[64][65], Wbuf[64][65], S2[64][65];
  const int h = blockIdx.x;
  const int tid = threadIdx.x;

  for (int e = tid; e < 4096; e += 256) {
    const int g = e >> 6, d = e & 63;
    T[g][d] = tok_num[h * 4096 + e] / (nrm[h * 64 + g] + 1e-5f);
  }
  for (int e = tid; e < 4096; e += 256) Wbuf[e >> 6][e & 63] = Wq[e];
  __syncthreads();

  const int g = tid >> 2, d0 = (tid & 3) * 16;
  float r[16];

#pragma unroll
  for (int j = 0; j < 16; ++j) r[j] = 0.f;
  for (int e = 0; e < 64; ++e) {
    const float tv = T[g][e];
#pragma unroll
    for (int j = 0; j < 16; ++j) r[j] = fmaf(tv, Wbuf[d0 + j][e], r[j]);
  }
#pragma unroll
  for (int j = 0; j < 16; ++j) Abuf[g][d0 + j] = r[j];
  __syncthreads();

  for (int e = tid; e < 4096; e += 256) Wbuf[e >> 6][e & 63] = Wk[e];
  __syncthreads();

#pragma unroll
  for (int j = 0; j < 16; ++j) r[j] = 0.f;
  for (int e = 0; e < 64; ++e) {
    const float tv = T[g][e];
#pragma unroll
    for (int j = 0; j < 16; ++j) r[j] = fmaf(tv, Wbuf[d0 + j][e], r[j]);
  }
#pragma unroll
  for (int j = 0; j < 16; ++j) Bbuf[g][d0 + j] = r[j];
  __syncthreads();

#pragma unroll
  for (int j = 0; j < 16; ++j) r[j] = 0.f;
  for (int e = 0; e < 64; ++e) {
    const float qv = Abuf[g][e] * 0.125f;
#pragma unroll
    for (int j = 0; j < 16; ++j) r[j] = fmaf(qv, Bbuf[d0 + j][e], r[j]);
  }
#pragma unroll
  for (int j = 0; j < 16; ++j) S2[g][d0 + j] = r[j];
  __syncthreads();

  if (tid < 64) {
    float mx = -1e30f;
    for (int j = 0; j < 64; ++j) mx = fmaxf(mx, S2[tid][j]);
    float sum = 0.f;
    for (int j = 0; j < 64; ++j) {
      const float e2 = expf(S2[tid][j] - mx);
      S2[tid][j] = e2;
      sum += e2;
    }
    const float inv = 1.0f / sum;
    for (int j = 0; j < 64; ++j) S2[tid][j] *= inv;
  }
  __syncthreads();

  for (int e = tid; e < 4096; e += 256) Wbuf[e >> 6][e & 63] = Wv[e];
  __syncthreads();

#pragma unroll
  for (int j = 0; j < 16; ++j) r[j] = 0.f;
  for (int e = 0; e < 64; ++e) {
    const float tv = T[g][e];
#pragma unroll
    for (int j = 0; j < 16; ++j) r[j] = fmaf(tv, Wbuf[d0 + j][e], r[j]);
  }
  __syncthreads();
#pragma unroll
  for (int j = 0; j < 16; ++j) Bbuf[g][d0 + j] = r[j];
  __syncthreads();

#pragma unroll
  for (int j = 0; j < 16; ++j) r[j] = 0.f;
  for (int e = 0; e < 64; ++e) {
    const float sv = S2[g][e];
#pragma unroll
    for (int j = 0; j < 16; ++j) r[j] = fmaf(sv, Bbuf[e][d0 + j], r[j]);
  }
  __syncthreads();
#pragma unroll
  for (int j = 0; j < 16; ++j) Abuf[g][d0 + j] = r[j];
  for (int e = tid; e < 4096; e += 256) Wbuf[e >> 6][e & 63] = Wo[e];
  __syncthreads();

#pragma unroll
  for (int j = 0; j < 16; ++j) r[j] = 0.f;
  for (int e = 0; e < 64; ++e) {
    const float ov = Abuf[g][e];
#pragma unroll
    for (int j = 0; j < 16; ++j) r[j] = fmaf(ov, Wbuf[d0 + j][e], r[j]);
  }
#pragma unroll
  for (int j = 0; j < 16; ++j) o_out[h * 4096 + g * 64 + d0 + j] = r[j];
}

// ---------------------------------------------------------------------------
// K4b: M2T[j][hg] = sum_d o[hg][d] * W_out[j][h*64+d]  -> hi/lo bf16 planes
// ---------------------------------------------------------------------------
__global__ __launch_bounds__(256) void k4b_m2(
    const float* __restrict__ o, const float* __restrict__ Wout,
    u16* __restrict__ M2h, u16* __restrict__ M2l)
{
  const int j = blockIdx.x >> 1;
  const int hg = ((blockIdx.x & 1) << 8) + threadIdx.x;
  const int h = hg >> 6;
  const float* orow = &o[hg * 64];
  const float* wrow = &Wout[j * 512 + h * 64];
  float s = 0.f;
#pragma unroll
  for (int d = 0; d < 64; ++d) s = fmaf(orow[d], wrow[d], s);
  const u16 hb = f2bf(s);
  M2h[j * 512 + hg] = hb;
  M2l[j * 512 + hg] = f2bf(s - bf2f(hb));
}

// ---------------------------------------------------------------------------
extern "C" void kernel_launch(void* const* d_in, const int* in_sizes, int n_in,
                              void* d_out, int out_size, void* d_ws, size_t ws_size,
                              hipStream_t stream)
{
  const float* x      = (const float*)d_in[0];
  const float* W_x    = (const float*)d_in[1];
  const float* b_x    = (const float*)d_in[2];
  const float* W_sl   = (const float*)d_in[3];
  const float* b_sl   = (const float*)d_in[4];
  const float* W_t1   = (const float*)d_in[5];
  const float* b_t1   = (const float*)d_in[6];
  const float* W_t2   = (const float*)d_in[7];
  const float* b_t2   = (const float*)d_in[8];
  const float* t_bias = (const float*)d_in[9];
  const float* Wq     = (const float*)d_in[10];
  const float* Wk     = (const float*)d_in[11];
  const float* Wv     = (const float*)d_in[12];
  const float* Wo     = (const float*)d_in[13];
  const float* W_out  = (const float*)d_in[14];
  const float* b_out  = (const float*)d_in[15];

  float* out = (float*)d_out;
  float* xp = out;   // xp lives in d_out; overwritten by final GEMM

  char* ws = (char*)d_ws;
  u16*      Ahi   = (u16*)(ws);                  // x hi plane (GEMM1)
  u16*      Alo   = (u16*)(ws + 67108864);       // x lo plane (GEMM1)
  uint32_t* wcp   = (uint32_t*)(ws);             // packed wcat (after GEMM1)
  u16*      Bhi   = (u16*)(ws + 134217728);      // Wx hi, then M2T hi
  u16*      Blo   = (u16*)(ws + 134742016);      // Wx lo, then M2T lo
  float* tok_num  = (float*)(ws + 135266304);    // 131072 B
  float* nrm      = (float*)(ws + 135397376);    // 2048 B
  float* o_buf    = (float*)(ws + 135399424);    // 131072 B

  conv_split<<<2048, 256, 0, stream>>>(x, Ahi, Alo, 8388608);
  conv_split<<<256, 256, 0, stream>>>(W_x, Bhi, Blo, 65536);
  gemm_split<<<2048, 256, 0, stream>>>(Ahi, Alo, Bhi, Blo, b_x, xp);

  hipMemsetAsync(tok_num, 0, 133120, stream);  // tok_num + nrm (contiguous)

  k2_route<<<2048, 256, 0, stream>>>(xp, W_sl, b_sl, W_t1, b_t1, W_t2, b_t2,
                                     t_bias, wcp);             // overwrites x-split
  k3_pool<<<1024, 256, 0, stream>>>(xp, wcp, tok_num, nrm);
  k4_attn<<<8, 256, 0, stream>>>(tok_num, nrm, Wq, Wk, Wv, Wo, o_buf);
  k4b_m2<<<1024, 256, 0, stream>>>(o_buf, W_out, Bhi, Blo);    // overwrites Wx-split
  gemm_packA<<<2048, 256, 0, stream>>>(wcp, Bhi, Blo, b_out, out);
}

// Round 11
// 556.941 us; speedup vs baseline: 1.5687x; 1.0810x over previous
//
#include <hip/hip_runtime.h>
#include <stdint.h>

typedef unsigned short u16;
typedef __bf16 bf16x8 __attribute__((ext_vector_type(8)));
typedef float f32x4 __attribute__((ext_vector_type(4)));

// ---------------------------------------------------------------------------
// EideticPhysicsAttention: N=65536 tokens, HID=512, H=8 heads, D=64, G=64.
//   conv  : split f32 -> (hi,lo) bf16 planes for x and W_x
//   K1    gemm_split : xp = x @ W_x.T + b_x  -> PACKED u32 (hi|lo<<16) in d_out
//   K2    k2_route   : MFMA logits+t1 (A-frags via v_perm from packed xp),
//                      threefry-gumbel, softmax -> wcat packed u32 plane
//   K3    k3_pool    : MFMA pooling: tok_num[h,g,d] = sum_n w*x (3-term
//                      split-bf16, direct coalesced fragment gathers); nrm
//   K4a   k4_attn    : per-head 64-token attention -> o[h,g,d]
//   K4b   k4b_m2     : M2T[j][hg] hi/lo = sum_d o[hg][d]*W_out[j][h*64+d]
//   K5    gemm_packA : out = wcat @ M2T.T + b_out      (overwrites d_out)
// ---------------------------------------------------------------------------

__device__ __forceinline__ u16 f2bf(float f) {   // RNE bf16
  uint32_t u = __float_as_uint(f);
  uint32_t r = u + 0x7fffu + ((u >> 16) & 1u);
  return (u16)(r >> 16);
}
__device__ __forceinline__ float bf2f(u16 h) {
  return __uint_as_float(((uint32_t)h) << 16);
}

union BF8 { bf16x8 v; u16 u[8]; uint4 q4; };

__device__ __forceinline__ float gelu_fast(float x) {
  const float c = 0.79788456080286535588f;
  float z = c * fmaf(0.044715f, x * x * x, x);
  return x / (1.0f + __expf(-2.0f * z));
}

__device__ __forceinline__ uint32_t rotl32(uint32_t v, int s) {
  return (v << s) | (v >> (32 - s));
}

// JAX threefry2x32, key=(0,1) from jax.random.key(1), partitionable path.
__device__ __forceinline__ uint32_t threefry_bits(uint32_t idx) {
  const uint32_t k0 = 0u, k1 = 1u;
  const uint32_t k2 = 0x1BD11BDAu ^ k0 ^ k1;
  uint32_t x0 = 0u + k0;
  uint32_t x1 = idx + k1;
#define TF_R(r) { x0 += x1; x1 = rotl32(x1, r); x1 ^= x0; }
  TF_R(13) TF_R(15) TF_R(26) TF_R(6)
  x0 += k1; x1 += k2 + 1u;
  TF_R(17) TF_R(29) TF_R(16) TF_R(24)
  x0 += k2; x1 += k0 + 2u;
  TF_R(13) TF_R(15) TF_R(26) TF_R(6)
  x0 += k0; x1 += k1 + 3u;
  TF_R(17) TF_R(29) TF_R(16) TF_R(24)
  x0 += k1; x1 += k2 + 4u;
  TF_R(13) TF_R(15) TF_R(26) TF_R(6)
  x0 += k2; x1 += k0 + 5u;
#undef TF_R
  return x0 ^ x1;
}

__device__ __forceinline__ void gload_lds16(const void* g, void* l) {
  __builtin_amdgcn_global_load_lds(
      (const __attribute__((address_space(1))) void*)g,
      (__attribute__((address_space(3))) void*)l, 16, 0, 0);
}

// ---------------------------------------------------------------------------
// conv_split: f32 -> hi/lo bf16 planes (grid-stride over float4 quads)
// ---------------------------------------------------------------------------
__global__ __launch_bounds__(256) void conv_split(
    const float* __restrict__ in, u16* __restrict__ hi, u16* __restrict__ lo,
    int nq)
{
  for (int i = blockIdx.x * 256 + threadIdx.x; i < nq; i += gridDim.x * 256) {
    float4 v = ((const float4*)in)[i];
    ushort4 h, l;
    h.x = f2bf(v.x); l.x = f2bf(v.x - bf2f(h.x));
    h.y = f2bf(v.y); l.y = f2bf(v.y - bf2f(h.y));
    h.z = f2bf(v.z); l.z = f2bf(v.z - bf2f(h.z));
    h.w = f2bf(v.w); l.w = f2bf(v.w - bf2f(h.w));
    ((ushort4*)hi)[i] = h;
    ((ushort4*)lo)[i] = l;
  }
}

// ---------------------------------------------------------------------------
// gemm_split: Cp[m][j] = pack( sum_k (Ah+Al)[m][k]*(Bh+Bl)[j][k] + bias[j] )
// Output PACKED u32 (hi | lo<<16).  128x128 tile, BK=32, XCD swizzle.
// ---------------------------------------------------------------------------
__global__ __launch_bounds__(256) void gemm_split(
    const u16* __restrict__ Ah, const u16* __restrict__ Al,
    const u16* __restrict__ Bh, const u16* __restrict__ Bl,
    const float* __restrict__ bias, uint32_t* __restrict__ Cp)
{
  __shared__ u16 lds[4][4096];   // [Ah,Al,Bh,Bl][128 rows * 32 k] = 32 KB
  const int tid = threadIdx.x;
  const int lane = tid & 63;
  const int w = tid >> 6;
  const int vid = (blockIdx.x & 7) * 256 + (blockIdx.x >> 3);  // XCD swizzle
  const int bn = vid & 3;
  const int bm = vid >> 2;
  const int wr = w >> 1, wc = w & 1;

  f32x4 acc[4][4];
#pragma unroll
  for (int m = 0; m < 4; ++m)
#pragma unroll
    for (int n = 0; n < 4; ++n) acc[m][n] = (f32x4){0.f, 0.f, 0.f, 0.f};

  const int srow = lane >> 2;
  const int scol = (lane & 3) * 8;

  for (int kt = 0; kt < 16; ++kt) {
    const int k0 = kt * 32;
    __syncthreads();
#pragma unroll
    for (int i = 0; i < 8; ++i) {
      const int mat = i & 3;
      const int rb = w * 2 + (i >> 2);
      const int row = rb * 16 + srow;
      const u16* base = (mat == 0) ? Ah : (mat == 1) ? Al
                       : (mat == 2) ? Bh : Bl;
      const int tbase = (mat < 2) ? bm * 128 : bn * 128;
      const u16* src = base + (size_t)(tbase + row) * 512 + k0 + scol;
      gload_lds16(src, &lds[mat][rb * 512]);
    }
    __syncthreads();

    bf16x8 ah[4], al[4], bh_[4], bl_[4];
    const int co = (lane >> 4) * 8;
    const int rr = lane & 15;
#pragma unroll
    for (int f = 0; f < 4; ++f) {
      const int ra  = (wr * 64 + f * 16 + rr) * 32 + co;
      const int rb2 = (wc * 64 + f * 16 + rr) * 32 + co;
      ah[f]  = *(const bf16x8*)&lds[0][ra];
      al[f]  = *(const bf16x8*)&lds[1][ra];
      bh_[f] = *(const bf16x8*)&lds[2][rb2];
      bl_[f] = *(const bf16x8*)&lds[3][rb2];
    }
#pragma unroll
    for (int m = 0; m < 4; ++m)
#pragma unroll
      for (int n = 0; n < 4; ++n) {
        acc[m][n] = __builtin_amdgcn_mfma_f32_16x16x32_bf16(ah[m], bh_[n], acc[m][n], 0, 0, 0);
        acc[m][n] = __builtin_amdgcn_mfma_f32_16x16x32_bf16(ah[m], bl_[n], acc[m][n], 0, 0, 0);
        acc[m][n] = __builtin_amdgcn_mfma_f32_16x16x32_bf16(al[m], bh_[n], acc[m][n], 0, 0, 0);
      }
  }

  const int cn0 = lane & 15;
  const int rm0 = (lane >> 4) * 4;
#pragma unroll
  for (int n = 0; n < 4; ++n) {
    const int ng = bn * 128 + wc * 64 + n * 16 + cn0;
    const float bv = bias[ng];
#pragma unroll
    for (int m = 0; m < 4; ++m) {
      const int mg = bm * 128 + wr * 64 + m * 16 + rm0;
#pragma unroll
      for (int r = 0; r < 4; ++r) {
        const float v = acc[m][n][r] + bv;
        const u16 hb = f2bf(v);
        const u16 lb = f2bf(v - bf2f(hb));
        Cp[(size_t)(mg + r) * 512 + ng] = (uint32_t)hb | ((uint32_t)lb << 16);
      }
    }
  }
}

// ---------------------------------------------------------------------------
// gemm_packA: A PACKED u32 (hi|lo<<16); B hi/lo u16 planes; C = f32 out.
// ---------------------------------------------------------------------------
__global__ __launch_bounds__(256) void gemm_packA(
    const uint32_t* __restrict__ A, const u16* __restrict__ Bh,
    const u16* __restrict__ Bl, const float* __restrict__ bias,
    float* __restrict__ C)
{
  __shared__ uint32_t ldsA[128 * 32];              // 16 KB
  __shared__ u16 ldsBh[128 * 32], ldsBl[128 * 32]; // 8 + 8 KB
  const int tid = threadIdx.x;
  const int lane = tid & 63;
  const int w = tid >> 6;
  const int vid = (blockIdx.x & 7) * 256 + (blockIdx.x >> 3);  // XCD swizzle
  const int bn = vid & 3;
  const int bm = vid >> 2;
  const int wr = w >> 1, wcq = w & 1;

  f32x4 acc[4][4];
#pragma unroll
  for (int m = 0; m < 4; ++m)
#pragma unroll
    for (int n = 0; n < 4; ++n) acc[m][n] = (f32x4){0.f, 0.f, 0.f, 0.f};

  for (int kt = 0; kt < 16; ++kt) {
    const int k0 = kt * 32;
    __syncthreads();
#pragma unroll
    for (int i = 0; i < 4; ++i) {
      const int rb8 = i * 4 + w;
      const int row = rb8 * 8 + (lane >> 3);
      const uint32_t* src =
          A + (size_t)(bm * 128 + row) * 512 + k0 + (lane & 7) * 4;
      gload_lds16(src, &ldsA[rb8 * 8 * 32]);
    }
#pragma unroll
    for (int i = 0; i < 2; ++i) {
      const int rb16 = i * 4 + w;
      const int row = rb16 * 16 + (lane >> 2);
      const int sc = (lane & 3) * 8;
      gload_lds16(Bh + (size_t)(bn * 128 + row) * 512 + k0 + sc,
                  &ldsBh[rb16 * 16 * 32]);
      gload_lds16(Bl + (size_t)(bn * 128 + row) * 512 + k0 + sc,
                  &ldsBl[rb16 * 16 * 32]);
    }
    __syncthreads();

    bf16x8 ah[4], al[4], bh_[4], bl_[4];
    const int co = (lane >> 4) * 8;
    const int rr = lane & 15;
#pragma unroll
    for (int f = 0; f < 4; ++f) {
      const int ra = (wr * 64 + f * 16 + rr) * 32 + co;
      const uint4 p0 = *(const uint4*)&ldsA[ra];
      const uint4 p1 = *(const uint4*)&ldsA[ra + 4];
      BF8 hv, lv;
      uint32_t* hd = (uint32_t*)&hv.q4;
      uint32_t* ld = (uint32_t*)&lv.q4;
      hd[0] = __builtin_amdgcn_perm(p0.y, p0.x, 0x05040100u);
      hd[1] = __builtin_amdgcn_perm(p0.w, p0.z, 0x05040100u);
      hd[2] = __builtin_amdgcn_perm(p1.y, p1.x, 0x05040100u);
      hd[3] = __builtin_amdgcn_perm(p1.w, p1.z, 0x05040100u);
      ld[0] = __builtin_amdgcn_perm(p0.y, p0.x, 0x07060302u);
      ld[1] = __builtin_amdgcn_perm(p0.w, p0.z, 0x07060302u);
      ld[2] = __builtin_amdgcn_perm(p1.y, p1.x, 0x07060302u);
      ld[3] = __builtin_amdgcn_perm(p1.w, p1.z, 0x07060302u);
      ah[f] = hv.v; al[f] = lv.v;
      const int rb2 = (wcq * 64 + f * 16 + rr) * 32 + co;
      bh_[f] = *(const bf16x8*)&ldsBh[rb2];
      bl_[f] = *(const bf16x8*)&ldsBl[rb2];
    }
#pragma unroll
    for (int m = 0; m < 4; ++m)
#pragma unroll
      for (int n = 0; n < 4; ++n) {
        acc[m][n] = __builtin_amdgcn_mfma_f32_16x16x32_bf16(ah[m], bh_[n], acc[m][n], 0, 0, 0);
        acc[m][n] = __builtin_amdgcn_mfma_f32_16x16x32_bf16(ah[m], bl_[n], acc[m][n], 0, 0, 0);
        acc[m][n] = __builtin_amdgcn_mfma_f32_16x16x32_bf16(al[m], bh_[n], acc[m][n], 0, 0, 0);
      }
  }

  const int cn0 = lane & 15;
  const int rm0 = (lane >> 4) * 4;
#pragma unroll
  for (int n = 0; n < 4; ++n) {
    const int ng = bn * 128 + wcq * 64 + n * 16 + cn0;
    const float bv = bias[ng];
#pragma unroll
    for (int m = 0; m < 4; ++m) {
      const int mg = bm * 128 + wr * 64 + m * 16 + rm0;
#pragma unroll
      for (int r = 0; r < 4; ++r)
        C[(size_t)(mg + r) * 512 + ng] = acc[m][n][r] + bv;
    }
  }
}

// ---------------------------------------------------------------------------
// K2: MFMA routing; xp read PACKED (A-frags via v_perm). Per-wave LDS
// transpose -> coalesced packed u32 stores.
// ---------------------------------------------------------------------------
__global__ __launch_bounds__(256, 4) void k2_route(
    const uint32_t* __restrict__ xpq, const float* __restrict__ Wsl,
    const float* __restrict__ bsl, const float* __restrict__ Wt1,
    const float* __restrict__ bt1, const float* __restrict__ Wt2,
    const float* __restrict__ bt2, const float* __restrict__ tbias,
    uint32_t* __restrict__ wcp)
{
  __shared__ u16 Wf[2][8][2][64][8];      // frag-ordered W planes, 32 KB
  __shared__ uint32_t wbuf[4][16][68];    // per-wave transpose, hi|lo<<16

  const int tid = threadIdx.x;
  const int l = tid & 63, wid = tid >> 6;
  const int l15 = l & 15, q = l >> 4;
  const int h = blockIdx.x >> 8;
  const int chunk = blockIdx.x & 255;

  // ---- stage W fragments (once per block) ----
#pragma unroll
  for (int it = 0; it < 8; ++it) {
    const int slot = tid + it * 256;
    const int p = slot >> 10;
    const int rest = slot & 1023;
    const int nn = rest >> 7;
    const int kk = (rest >> 6) & 1;
    const int sl = rest & 63;
    const int row = nn * 16 + (sl & 15);
    const int kb = kk * 32 + (sl >> 4) * 8;
    const float* src = (row < 64) ? (Wsl + row * 64 + kb)
                                  : (Wt1 + (row - 64) * 64 + kb);
#pragma unroll
    for (int e = 0; e < 8; ++e) {
      const float v = src[e];
      const u16 hb = f2bf(v);
      Wf[p][nn][kk][sl][e] = (p == 0) ? hb : f2bf(v - bf2f(hb));
    }
  }
  __syncthreads();

  float bslv[4], bt1v[4], wt2v[4];
#pragma unroll
  for (int j = 0; j < 4; ++j) {
    bslv[j] = bsl[j * 16 + l15];
    bt1v[j] = bt1[j * 16 + l15];
    wt2v[j] = Wt2[j * 16 + l15];
  }
  const float bt2v = bt2[0], tbv = tbias[h];

#pragma unroll 1
  for (int tm = 0; tm < 4; ++tm) {
    const int n0t = chunk * 256 + (tm >> 1) * 128 + wid * 32 + (tm & 1) * 16;

    // ---- A fragments from packed xp via v_perm ----
    bf16x8 ah[2], al[2];
#pragma unroll
    for (int kk = 0; kk < 2; ++kk) {
      const uint32_t* sp = xpq + (size_t)(n0t + l15) * 512 + h * 64
                           + kk * 32 + q * 8;
      const uint4 p0 = *(const uint4*)sp;
      const uint4 p1 = *(const uint4*)(sp + 4);
      BF8 hv, lv;
      uint32_t* hd = (uint32_t*)&hv.q4;
      uint32_t* ld = (uint32_t*)&lv.q4;
      hd[0] = __builtin_amdgcn_perm(p0.y, p0.x, 0x05040100u);
      hd[1] = __builtin_amdgcn_perm(p0.w, p0.z, 0x05040100u);
      hd[2] = __builtin_amdgcn_perm(p1.y, p1.x, 0x05040100u);
      hd[3] = __builtin_amdgcn_perm(p1.w, p1.z, 0x05040100u);
      ld[0] = __builtin_amdgcn_perm(p0.y, p0.x, 0x07060302u);
      ld[1] = __builtin_amdgcn_perm(p0.w, p0.z, 0x07060302u);
      ld[2] = __builtin_amdgcn_perm(p1.y, p1.x, 0x07060302u);
      ld[3] = __builtin_amdgcn_perm(p1.w, p1.z, 0x07060302u);
      ah[kk] = hv.v; al[kk] = lv.v;
    }

    // ---- MFMA: [16 tok] x [128 cols], K=64, 3-term ----
    f32x4 acc[8];
#pragma unroll
    for (int n = 0; n < 8; ++n) acc[n] = (f32x4){0.f, 0.f, 0.f, 0.f};
#pragma unroll
    for (int kk = 0; kk < 2; ++kk)
#pragma unroll
      for (int nn = 0; nn < 8; ++nn) {
        BF8 whf, wlf;
        whf.q4 = *(const uint4*)&Wf[0][nn][kk][l][0];
        wlf.q4 = *(const uint4*)&Wf[1][nn][kk][l][0];
        acc[nn] = __builtin_amdgcn_mfma_f32_16x16x32_bf16(ah[kk], whf.v, acc[nn], 0, 0, 0);
        acc[nn] = __builtin_amdgcn_mfma_f32_16x16x32_bf16(ah[kk], wlf.v, acc[nn], 0, 0, 0);
        acc[nn] = __builtin_amdgcn_mfma_f32_16x16x32_bf16(al[kk], whf.v, acc[nn], 0, 0, 0);
      }

    // ---- temperature per r ----
    float itv[4];
#pragma unroll
    for (int r = 0; r < 4; ++r) {
      float part = 0.f;
#pragma unroll
      for (int j = 0; j < 4; ++j)
        part += gelu_fast(acc[4 + j][r] + bt1v[j]) * wt2v[j];
      part += __shfl_xor(part, 1);
      part += __shfl_xor(part, 2);
      part += __shfl_xor(part, 4);
      part += __shfl_xor(part, 8);
      const float tval = gelu_fast(part + bt2v) + tbv;
      itv[r] = 1.0f / fmaxf(tval, 0.01f);
    }

    // ---- logits: bias + threefry-gumbel + /t ----
    const uint32_t pbase = ((uint32_t)((h << 16) | (n0t + q * 4))) << 6;
#pragma unroll
    for (int j = 0; j < 4; ++j) {
      const uint32_t cc = j * 16 + l15;
#pragma unroll
      for (int r = 0; r < 4; ++r) {
        const uint32_t bits = threefry_bits(pbase + ((uint32_t)r << 6) + cc);
        const float u = __uint_as_float((bits >> 9) | 0x3f800000u) - 1.0f;
        const float gin = -__logf(u + 1e-8f);
        const float gn = -__logf(gin + 1e-8f);
        acc[j][r] = (acc[j][r] + bslv[j] + gn) * itv[r];
      }
    }

    // ---- softmax over cols ----
#pragma unroll
    for (int r = 0; r < 4; ++r) {
      float mx = fmaxf(fmaxf(acc[0][r], acc[1][r]),
                       fmaxf(acc[2][r], acc[3][r]));
      mx = fmaxf(mx, __shfl_xor(mx, 1));
      mx = fmaxf(mx, __shfl_xor(mx, 2));
      mx = fmaxf(mx, __shfl_xor(mx, 4));
      mx = fmaxf(mx, __shfl_xor(mx, 8));
      float se = 0.f;
#pragma unroll
      for (int j = 0; j < 4; ++j) {
        const float e = __expf(acc[j][r] - mx);
        acc[j][r] = e;
        se += e;
      }
      se += __shfl_xor(se, 1);
      se += __shfl_xor(se, 2);
      se += __shfl_xor(se, 4);
      se += __shfl_xor(se, 8);
      const float inv = 1.0f / se;
#pragma unroll
      for (int j = 0; j < 4; ++j) acc[j][r] *= inv;
    }

    // ---- pack hi|lo into per-wave LDS transpose ----
#pragma unroll
    for (int j = 0; j < 4; ++j)
#pragma unroll
      for (int r = 0; r < 4; ++r) {
        const float wv = acc[j][r];
        const u16 hb = f2bf(wv);
        const u16 lb = f2bf(wv - bf2f(hb));
        wbuf[wid][q * 4 + r][j * 16 + l15] = (uint32_t)hb | ((uint32_t)lb << 16);
      }
    __syncthreads();

    // ---- coalesced packed stores: 16 tok x 16 uint4 -> 64 lanes x 4 ----
#pragma unroll
    for (int it = 0; it < 4; ++it) {
      const int t = l >> 2;
      const int qq = (l & 3) + it * 4;    // 0..15
      const uint4 v = *(const uint4*)&wbuf[wid][t][qq * 4];
      *(uint4*)(wcp + (size_t)(n0t + t) * 512 + h * 64 + qq * 4) = v;
    }
    __syncthreads();
  }
}

// ---------------------------------------------------------------------------
// K3: MFMA pooling. Per head: tok_num[g,d] = sum_n w[n,g]*x[n,d] (K=65536).
// Grid = 8 heads x 64 chunks (1024 tok); 4 waves x 256 tok; per wave 8 tiles
// of 32 tokens. Fragment gathers straight from global (each load instr =
// 4 full 64B lines, every line fetched exactly once). 3-term split-bf16.
// nrm[h,g] from w-fragments (per-lane partial + shfl_xor over q-groups).
// ---------------------------------------------------------------------------
__global__ __launch_bounds__(256, 2) void k3_pool(
    const uint32_t* __restrict__ xpq, const uint32_t* __restrict__ wcp,
    float* __restrict__ tok_num, float* __restrict__ nrm)
{
  __shared__ float red[64][65];
  const int h = blockIdx.x >> 6;
  const int chunk = blockIdx.x & 63;
  const int lane = threadIdx.x & 63;
  const int wid = threadIdx.x >> 6;
  const int l15 = lane & 15, q = lane >> 4;

  f32x4 acc[4][4];
#pragma unroll
  for (int m = 0; m < 4; ++m)
#pragma unroll
    for (int n = 0; n < 4; ++n) acc[m][n] = (f32x4){0.f, 0.f, 0.f, 0.f};
  float csum[4] = {0.f, 0.f, 0.f, 0.f};

  const int tw = chunk * 1024 + wid * 256;
#pragma unroll 1
  for (int tt = 0; tt < 8; ++tt) {
    const int t0 = tw + tt * 32;
    uint32_t wreg[4][8], xreg[4][8];
#pragma unroll
    for (int e = 0; e < 8; ++e) {
      const size_t rb = (size_t)(t0 + q * 8 + e) * 512 + h * 64 + l15;
#pragma unroll
      for (int m = 0; m < 4; ++m) {
        wreg[m][e] = wcp[rb + m * 16];
        xreg[m][e] = xpq[rb + m * 16];
      }
    }
    bf16x8 whf[4], wlf[4], xhf[4], xlf[4];
#pragma unroll
    for (int m = 0; m < 4; ++m) {
      BF8 hv, lv, xh, xl;
      uint32_t* hd = (uint32_t*)&hv.q4;
      uint32_t* ld = (uint32_t*)&lv.q4;
      uint32_t* xhd = (uint32_t*)&xh.q4;
      uint32_t* xld = (uint32_t*)&xl.q4;
#pragma unroll
      for (int p = 0; p < 4; ++p) {
        hd[p]  = __builtin_amdgcn_perm(wreg[m][2*p+1], wreg[m][2*p], 0x05040100u);
        ld[p]  = __builtin_amdgcn_perm(wreg[m][2*p+1], wreg[m][2*p], 0x07060302u);
        xhd[p] = __builtin_amdgcn_perm(xreg[m][2*p+1], xreg[m][2*p], 0x05040100u);
        xld[p] = __builtin_amdgcn_perm(xreg[m][2*p+1], xreg[m][2*p], 0x07060302u);
      }
      whf[m] = hv.v; wlf[m] = lv.v; xhf[m] = xh.v; xlf[m] = xl.v;
#pragma unroll
      for (int e = 0; e < 8; ++e)
        csum[m] += __uint_as_float(wreg[m][e] << 16)
                 + __uint_as_float(wreg[m][e] & 0xffff0000u);
    }
#pragma unroll
    for (int m = 0; m < 4; ++m)
#pragma unroll
      for (int n = 0; n < 4; ++n) {
        acc[m][n] = __builtin_amdgcn_mfma_f32_16x16x32_bf16(whf[m], xhf[n], acc[m][n], 0, 0, 0);
        acc[m][n] = __builtin_amdgcn_mfma_f32_16x16x32_bf16(whf[m], xlf[n], acc[m][n], 0, 0, 0);
        acc[m][n] = __builtin_amdgcn_mfma_f32_16x16x32_bf16(wlf[m], xhf[n], acc[m][n], 0, 0, 0);
      }
  }

  // nrm: reduce csum over q-groups, lanes q==0 add 4 g-values each
#pragma unroll
  for (int m = 0; m < 4; ++m) {
    csum[m] += __shfl_xor(csum[m], 16);
    csum[m] += __shfl_xor(csum[m], 32);
  }
  if (q == 0) {
#pragma unroll
    for (int m = 0; m < 4; ++m)
      atomicAdd(&nrm[h * 64 + m * 16 + l15], csum[m]);
  }

  // cross-wave reduce (bank pattern: (q*4+l15) -> 2-way, free)
  for (int w = 0; w < 4; ++w) {
    if (wid == w) {
#pragma unroll
      for (int m = 0; m < 4; ++m)
#pragma unroll
        for (int n = 0; n < 4; ++n)
#pragma unroll
          for (int r = 0; r < 4; ++r) {
            const int g = m * 16 + q * 4 + r;
            const int d = n * 16 + l15;
            if (w == 0) red[g][d] = acc[m][n][r];
            else        red[g][d] += acc[m][n][r];
          }
    }
    __syncthreads();
  }
  for (int e = threadIdx.x; e < 4096; e += 256)
    atomicAdd(&tok_num[h * 4096 + e], red[e >> 6][e & 63]);
}

// ---------------------------------------------------------------------------
// K4a: per-head attention over G=64 slice tokens. One block per head.
// ---------------------------------------------------------------------------
__global__ __launch_bounds__(256) void k4_attn(
    const float* __restrict__ tok_num, const float* __restrict__ nrm,
    const float* __restrict__ Wq, const float* __restrict__ Wk,
    const float* __restrict__ Wv, const float* __restrict__ Wo,
    float* __restrict__ o_out)
{
  __shared__ float T[64][65], Abuf[64][65], Bbuf[64][65], Wbuf[64][65], S2[64][65];
  const int h = blockIdx.x;
  const int tid = threadIdx.x;

  for (int e = tid; e < 4096; e += 256) {
    const int g = e >> 6, d = e & 63;
    T[g][d] = tok_num[h * 4096 + e] / (nrm[h * 64 + g] + 1e-5f);
  }
  for (int e = tid; e < 4096; e += 256) Wbuf[e >> 6][e & 63] = Wq[e];
  __syncthreads();

  const int g = tid >> 2, d0 = (tid & 3) * 16;
  float r[16];

#pragma unroll
  for (int j = 0; j < 16; ++j) r[j] = 0.f;
  for (int e = 0; e < 64; ++e) {
    const float tv = T[g][e];
#pragma unroll
    for (int j = 0; j < 16; ++j) r[j] = fmaf(tv, Wbuf[d0 + j][e], r[j]);
  }
#pragma unroll
  for (int j = 0; j < 16; ++j) Abuf[g][d0 + j] = r[j];
  __syncthreads();

  for (int e = tid; e < 4096; e += 256) Wbuf[e >> 6][e & 63] = Wk[e];
  __syncthreads();

#pragma unroll
  for (int j = 0; j < 16; ++j) r[j] = 0.f;
  for (int e = 0; e < 64; ++e) {
    const float tv = T[g][e];
#pragma unroll
    for (int j = 0; j < 16; ++j) r[j] = fmaf(tv, Wbuf[d0 + j][e], r[j]);
  }
#pragma unroll
  for (int j = 0; j < 16; ++j) Bbuf[g][d0 + j] = r[j];
  __syncthreads();

#pragma unroll
  for (int j = 0; j < 16; ++j) r[j] = 0.f;
  for (int e = 0; e < 64; ++e) {
    const float qv = Abuf[g][e] * 0.125f;
#pragma unroll
    for (int j = 0; j < 16; ++j) r[j] = fmaf(qv, Bbuf[d0 + j][e], r[j]);
  }
#pragma unroll
  for (int j = 0; j < 16; ++j) S2[g][d0 + j] = r[j];
  __syncthreads();

  if (tid < 64) {
    float mx = -1e30f;
    for (int j = 0; j < 64; ++j) mx = fmaxf(mx, S2[tid][j]);
    float sum = 0.f;
    for (int j = 0; j < 64; ++j) {
      const float e2 = expf(S2[tid][j] - mx);
      S2[tid][j] = e2;
      sum += e2;
    }
    const float inv = 1.0f / sum;
    for (int j = 0; j < 64; ++j) S2[tid][j] *= inv;
  }
  __syncthreads();

  for (int e = tid; e < 4096; e += 256) Wbuf[e >> 6][e & 63] = Wv[e];
  __syncthreads();

#pragma unroll
  for (int j = 0; j < 16; ++j) r[j] = 0.f;
  for (int e = 0; e < 64; ++e) {
    const float tv = T[g][e];
#pragma unroll
    for (int j = 0; j < 16; ++j) r[j] = fmaf(tv, Wbuf[d0 + j][e], r[j]);
  }
  __syncthreads();
#pragma unroll
  for (int j = 0; j < 16; ++j) Bbuf[g][d0 + j] = r[j];
  __syncthreads();

#pragma unroll
  for (int j = 0; j < 16; ++j) r[j] = 0.f;
  for (int e = 0; e < 64; ++e) {
    const float sv = S2[g][e];
#pragma unroll
    for (int j = 0; j < 16; ++j) r[j] = fmaf(sv, Bbuf[e][d0 + j], r[j]);
  }
  __syncthreads();
#pragma unroll
  for (int j = 0; j < 16; ++j) Abuf[g][d0 + j] = r[j];
  for (int e = tid; e < 4096; e += 256) Wbuf[e >> 6][e & 63] = Wo[e];
  __syncthreads();

#pragma unroll
  for (int j = 0; j < 16; ++j) r[j] = 0.f;
  for (int e = 0; e < 64; ++e) {
    const float ov = Abuf[g][e];
#pragma unroll
    for (int j = 0; j < 16; ++j) r[j] = fmaf(ov, Wbuf[d0 + j][e], r[j]);
  }
#pragma unroll
  for (int j = 0; j < 16; ++j) o_out[h * 4096 + g * 64 + d0 + j] = r[j];
}

// ---------------------------------------------------------------------------
// K4b: M2T[j][hg] = sum_d o[hg][d] * W_out[j][h*64+d]  -> hi/lo bf16 planes
// ---------------------------------------------------------------------------
__global__ __launch_bounds__(256) void k4b_m2(
    const float* __restrict__ o, const float* __restrict__ Wout,
    u16* __restrict__ M2h, u16* __restrict__ M2l)
{
  const int j = blockIdx.x >> 1;
  const int hg = ((blockIdx.x & 1) << 8) + threadIdx.x;
  const int h = hg >> 6;
  const float* orow = &o[hg * 64];
  const float* wrow = &Wout[j * 512 + h * 64];
  float s = 0.f;
#pragma unroll
  for (int d = 0; d < 64; ++d) s = fmaf(orow[d], wrow[d], s);
  const u16 hb = f2bf(s);
  M2h[j * 512 + hg] = hb;
  M2l[j * 512 + hg] = f2bf(s - bf2f(hb));
}

// ---------------------------------------------------------------------------
extern "C" void kernel_launch(void* const* d_in, const int* in_sizes, int n_in,
                              void* d_out, int out_size, void* d_ws, size_t ws_size,
                              hipStream_t stream)
{
  const float* x      = (const float*)d_in[0];
  const float* W_x    = (const float*)d_in[1];
  const float* b_x    = (const float*)d_in[2];
  const float* W_sl   = (const float*)d_in[3];
  const float* b_sl   = (const float*)d_in[4];
  const float* W_t1   = (const float*)d_in[5];
  const float* b_t1   = (const float*)d_in[6];
  const float* W_t2   = (const float*)d_in[7];
  const float* b_t2   = (const float*)d_in[8];
  const float* t_bias = (const float*)d_in[9];
  const float* Wq     = (const float*)d_in[10];
  const float* Wk     = (const float*)d_in[11];
  const float* Wv     = (const float*)d_in[12];
  const float* Wo     = (const float*)d_in[13];
  const float* W_out  = (const float*)d_in[14];
  const float* b_out  = (const float*)d_in[15];

  float* out = (float*)d_out;
  uint32_t* xpq = (uint32_t*)d_out;  // packed xp lives in d_out until GEMM2

  char* ws = (char*)d_ws;
  u16*      Ahi   = (u16*)(ws);                  // x hi plane (GEMM1)
  u16*      Alo   = (u16*)(ws + 67108864);       // x lo plane (GEMM1)
  uint32_t* wcp   = (uint32_t*)(ws);             // packed wcat (after GEMM1)
  u16*      Bhi   = (u16*)(ws + 134217728);      // Wx hi, then M2T hi
  u16*      Blo   = (u16*)(ws + 134742016);      // Wx lo, then M2T lo
  float* tok_num  = (float*)(ws + 135266304);    // 131072 B
  float* nrm      = (float*)(ws + 135397376);    // 2048 B
  float* o_buf    = (float*)(ws + 135399424);    // 131072 B

  conv_split<<<2048, 256, 0, stream>>>(x, Ahi, Alo, 8388608);
  conv_split<<<256, 256, 0, stream>>>(W_x, Bhi, Blo, 65536);
  gemm_split<<<2048, 256, 0, stream>>>(Ahi, Alo, Bhi, Blo, b_x, xpq);

  hipMemsetAsync(tok_num, 0, 133120, stream);  // tok_num + nrm (contiguous)

  k2_route<<<2048, 256, 0, stream>>>(xpq, W_sl, b_sl, W_t1, b_t1, W_t2, b_t2,
                                     t_bias, wcp);             // overwrites x-split
  k3_pool<<<512, 256, 0, stream>>>(xpq, wcp, tok_num, nrm);
  k4_attn<<<8, 256, 0, stream>>>(tok_num, nrm, Wq, Wk, Wv, Wo, o_buf);
  k4b_m2<<<1024, 256, 0, stream>>>(o_buf, W_out, Bhi, Blo);    // overwrites Wx-split
  gemm_packA<<<2048, 256, 0, stream>>>(wcp, Bhi, Blo, b_out, out);
}